// Round 16
// baseline (1488.519 us; speedup 1.0000x reference)
//
#include <hip/hip_runtime.h>
#include <math.h>

#define N_NODES 50000
#define M_PAD 50048            // 391 * 128
#define NUM_EDGES 800000
#define NG 8
#define HID 256
#define RHD 128
#define NEXP 4
#define OUTD 6

typedef unsigned short bf16_t;
using f32x4  = __attribute__((ext_vector_type(4))) float;
using bf16x8 = __attribute__((ext_vector_type(8))) short;

__device__ __forceinline__ float bf2f(unsigned short u) {
  union { unsigned int i; float f; } v; v.i = ((unsigned int)u) << 16; return v.f;
}
__device__ __forceinline__ unsigned short f2bf(float f) {
  union { float f; unsigned int i; } v; v.f = f;
  unsigned int x = v.i;
  unsigned int r = x + 0x7fffu + ((x >> 16) & 1u);  // RNE
  return (unsigned short)(r >> 16);
}
__device__ __forceinline__ float readlane_f(float v, int lane) {
  return __int_as_float(__builtin_amdgcn_readlane(__float_as_int(v), lane));
}

// ---------------- zero init ----------------
__global__ void k_zero(int* __restrict__ deg, int* __restrict__ n_cnt,
                       int* __restrict__ e_cnt) {
  int i = blockIdx.x * blockDim.x + threadIdx.x;
  if (i < N_NODES) deg[i] = 0;
  if (i < NG) { n_cnt[i] = 0; e_cnt[i] = 0; }
}

// ---------------- graph stats ----------------
__global__ void k_count_nodes(const int* __restrict__ batch, int* __restrict__ n_cnt) {
  __shared__ int hist[NG];
  int t = threadIdx.x;
  if (t < NG) hist[t] = 0;
  __syncthreads();
  int i = blockIdx.x * blockDim.x + t;
  if (i < N_NODES) atomicAdd(&hist[batch[i]], 1);
  __syncthreads();
  if (t < NG && hist[t]) atomicAdd(&n_cnt[t], hist[t]);
}

__global__ void k_count_edges(const int* __restrict__ edge, const int* __restrict__ batch,
                              int* __restrict__ e_cnt, int* __restrict__ deg) {
  __shared__ int hist[NG];
  int t = threadIdx.x;
  if (t < NG) hist[t] = 0;
  __syncthreads();
  int i = blockIdx.x * blockDim.x + t;
  if (i < NUM_EDGES) {
    int s = edge[i];
    int d = edge[NUM_EDGES + i];
    atomicAdd(&hist[batch[s]], 1);
    atomicAdd(&deg[d], 1);
  }
  __syncthreads();
  if (t < NG && hist[t]) atomicAdd(&e_cnt[t], hist[t]);
}

// numpy-faithful f32 stats (frozen: razor-sensitive)
__device__ __forceinline__ float tree8(const float* v) {
  float s01 = __fadd_rn(v[0], v[1]);
  float s23 = __fadd_rn(v[2], v[3]);
  float s45 = __fadd_rn(v[4], v[5]);
  float s67 = __fadd_rn(v[6], v[7]);
  return __fadd_rn(__fadd_rn(s01, s23), __fadd_rn(s45, s67));
}

__global__ void k_graph_stats(const int* __restrict__ n_cnt, const int* __restrict__ e_cnt,
                              float* __restrict__ gf, float* __restrict__ lnn) {
  if (threadIdx.x != 0 || blockIdx.x != 0) return;
  float logn[NG], loge[NG];
  for (int g = 0; g < NG; ++g) {
    float nf = fmaxf((float)n_cnt[g], 1.0f);
    logn[g] = (float)log((double)nf);
    float ef = fmaxf((float)e_cnt[g], 0.0f);
    loge[g] = (float)log1p((double)ef);
  }
  float m0 = __fdiv_rn(tree8(logn), 8.0f);
  float m1 = __fdiv_rn(tree8(loge), 8.0f);
  float sq0[NG], sq1[NG];
  float mn = 3.0e38f, mx = -3.0e38f;
  for (int g = 0; g < NG; ++g) {
    float d0 = __fsub_rn(logn[g], m0);
    float d1 = __fsub_rn(loge[g], m1);
    sq0[g] = __fmul_rn(d0, d0);
    sq1[g] = __fmul_rn(d1, d1);
    mn = fminf(mn, logn[g]); mx = fmaxf(mx, logn[g]);
  }
  float s0 = __fadd_rn(sqrtf(__fdiv_rn(tree8(sq0), 8.0f)), 1e-6f);
  float s1 = __fadd_rn(sqrtf(__fdiv_rn(tree8(sq1), 8.0f)), 1e-6f);
  float denom = __fadd_rn(__fsub_rn(mx, mn), 1e-6f);
  for (int g = 0; g < NG; ++g) {
    gf[g * 2 + 0] = __fdiv_rn(__fsub_rn(logn[g], m0), s0);
    gf[g * 2 + 1] = __fdiv_rn(__fsub_rn(loge[g], m1), s1);
    lnn[g] = __fdiv_rn(__fsub_rn(logn[g], mn), denom);
  }
}

// ---------------- CSR build ----------------
__global__ void k_scan(const int* __restrict__ deg, int* __restrict__ row_start,
                       int* __restrict__ cursor) {
  __shared__ int temp[1024];
  int tid = threadIdx.x;
  int carry = 0;
  for (int base = 0; base < N_NODES; base += 1024) {
    int i = base + tid;
    int v = (i < N_NODES) ? deg[i] : 0;
    temp[tid] = v;
    __syncthreads();
    for (int off = 1; off < 1024; off <<= 1) {
      int t = (tid >= off) ? temp[tid - off] : 0;
      __syncthreads();
      temp[tid] += t;
      __syncthreads();
    }
    int incl = temp[tid];
    if (i < N_NODES) {
      int e = carry + incl - v;
      row_start[i] = e;
      cursor[i] = e;
    }
    carry += temp[1023];
    __syncthreads();
  }
  if (tid == 0) row_start[N_NODES] = carry;
}

__global__ void k_fill(const int* __restrict__ edge, int* __restrict__ cursor,
                       int* __restrict__ csr_src) {
  int i = blockIdx.x * blockDim.x + threadIdx.x;
  if (i < NUM_EDGES) {
    int d = edge[NUM_EDGES + i];
    int p = atomicAdd(&cursor[d], 1);
    csr_src[p] = edge[i];
  }
}

// ---------------- encoder layer 1 (frozen) -----------------------------------------
__global__ void k_enc1(const float* __restrict__ x, const float* __restrict__ w1,
                       const float* __restrict__ b1, float* __restrict__ t) {
  __shared__ float W[6 * 256];
  __shared__ float xs[16][6];
  int tid = threadIdx.x;
  for (int i = tid; i < 6 * 256; i += 256) W[i] = w1[i];
  int base = blockIdx.x * 16;
  if (tid < 96) {
    int n = tid / 6, k = tid % 6;
    int node = base + n;
    xs[n][k] = (node < N_NODES) ? x[node * 16 + 4 + k] : 0.f;
  }
  __syncthreads();
  float b = b1[tid];
  for (int n = 0; n < 16; ++n) {
    int node = base + n;
    if (node >= N_NODES) break;
    float acc = 0.f;
#pragma unroll
    for (int k = 0; k < 6; ++k) acc = __fmaf_rn(xs[n][k], W[k * 256 + tid], acc);
    t[node * 256 + tid] = fmaxf(__fadd_rn(acc, b), 0.f);
  }
}

// ---------------- fp32 SIMT GEMM (frozen math; epilogue also emits bf16 copy) -------
__global__ __launch_bounds__(256, 2) void k_gemm_enc(
    const float* __restrict__ A, const float* __restrict__ W0,
    const float* __restrict__ bias, float* __restrict__ C,
    bf16_t* __restrict__ Cb, int M) {
  __shared__ float As[16][132];
  __shared__ float Ws[16][128];
  const int tid = threadIdx.x;
  const int tx = tid & 15;
  const int ty = tid >> 4;
  const int rowBase = blockIdx.x * 128;
  const int colBase = blockIdx.y * 128;

  float acc[2][2][4][4];
#pragma unroll
  for (int a = 0; a < 2; ++a)
#pragma unroll
    for (int b = 0; b < 2; ++b)
#pragma unroll
      for (int i = 0; i < 4; ++i)
#pragma unroll
        for (int j = 0; j < 4; ++j) acc[a][b][i][j] = 0.f;

  for (int kt = 0; kt < 16; ++kt) {
    const int kb = kt * 16;
#pragma unroll
    for (int l = 0; l < 2; ++l) {
      int idx = tid + l * 256;
      int m = idx >> 2;
      int kq = (idx & 3) * 4;
      int arow = rowBase + m;
      float4 av = make_float4(0.f, 0.f, 0.f, 0.f);
      if (arow < M) av = *reinterpret_cast<const float4*>(&A[arow * 256 + kb + kq]);
      As[kq + 0][m] = av.x; As[kq + 1][m] = av.y;
      As[kq + 2][m] = av.z; As[kq + 3][m] = av.w;
    }
#pragma unroll
    for (int l = 0; l < 2; ++l) {
      int idx = tid + l * 256;
      int k = idx >> 5;
      int nq = (idx & 31) * 4;
      float4 wv = *reinterpret_cast<const float4*>(&W0[(kb + k) * 256 + colBase + nq]);
      *reinterpret_cast<float4*>(&Ws[k][nq]) = wv;
    }
    __syncthreads();
#pragma unroll
    for (int k = 0; k < 16; ++k) {
      float4 a0 = *reinterpret_cast<const float4*>(&As[k][ty * 4]);
      float4 a1 = *reinterpret_cast<const float4*>(&As[k][64 + ty * 4]);
      float4 w0 = *reinterpret_cast<const float4*>(&Ws[k][tx * 4]);
      float4 w1 = *reinterpret_cast<const float4*>(&Ws[k][64 + tx * 4]);
      float ar[2][4] = {{a0.x, a0.y, a0.z, a0.w}, {a1.x, a1.y, a1.z, a1.w}};
      float wr[2][4] = {{w0.x, w0.y, w0.z, w0.w}, {w1.x, w1.y, w1.z, w1.w}};
#pragma unroll
      for (int ri = 0; ri < 2; ++ri)
#pragma unroll
        for (int i = 0; i < 4; ++i)
#pragma unroll
          for (int ci = 0; ci < 2; ++ci)
#pragma unroll
            for (int j = 0; j < 4; ++j)
              acc[ri][ci][i][j] = __fmaf_rn(ar[ri][i], wr[ci][j], acc[ri][ci][i][j]);
    }
    __syncthreads();
  }
  float4 bv0 = *reinterpret_cast<const float4*>(&bias[colBase + tx * 4]);
  float4 bv1 = *reinterpret_cast<const float4*>(&bias[colBase + 64 + tx * 4]);
  float bb[2][4] = {{bv0.x, bv0.y, bv0.z, bv0.w}, {bv1.x, bv1.y, bv1.z, bv1.w}};
#pragma unroll
  for (int ri = 0; ri < 2; ++ri) {
#pragma unroll
    for (int i = 0; i < 4; ++i) {
      int row = rowBase + ri * 64 + ty * 4 + i;
      if (row < M) {
#pragma unroll
        for (int ci = 0; ci < 2; ++ci) {
          float o[4];
#pragma unroll
          for (int j = 0; j < 4; ++j)
            o[j] = __fadd_rn(acc[ri][ci][i][j], bb[ci][j]);
          *reinterpret_cast<float4*>(&C[row * 256 + colBase + ci * 64 + tx * 4]) =
              make_float4(o[0], o[1], o[2], o[3]);
          ushort4 ob = make_ushort4(f2bf(o[0]), f2bf(o[1]), f2bf(o[2]), f2bf(o[3]));
          *reinterpret_cast<ushort4*>(&Cb[(size_t)row * 256 + colBase + ci * 64 + tx * 4]) = ob;
        }
      }
    }
  }
}

// ---------------- weight prep: transpose f32 [k][n] -> bf16 [n][k] ------------------
__global__ void k_wprep(const float* __restrict__ w_rel, const float* __restrict__ w_root,
                        bf16_t* __restrict__ WT) {
  __shared__ bf16_t tile[64][258];
  int m = blockIdx.x;
  int k0 = blockIdx.y * 64;
  const float* src = (m < 8) ? (w_rel + (size_t)m * 65536)
                             : (w_root + (size_t)(m - 8) * 65536);
  bf16_t* dst = WT + (size_t)m * 65536;
  int tid = threadIdx.x;
  for (int r = 0; r < 64; ++r)
    tile[r][tid] = f2bf(src[(k0 + r) * 256 + tid]);
  __syncthreads();
  for (int c = 0; c < 64; c += 8) {
    ushort4 lo, hi;
    lo.x = tile[c + 0][tid]; lo.y = tile[c + 1][tid];
    lo.z = tile[c + 2][tid]; lo.w = tile[c + 3][tid];
    hi.x = tile[c + 4][tid]; hi.y = tile[c + 5][tid];
    hi.z = tile[c + 6][tid]; hi.w = tile[c + 7][tid];
    *reinterpret_cast<ushort4*>(&dst[tid * 256 + k0 + c]) = lo;
    *reinterpret_cast<ushort4*>(&dst[tid * 256 + k0 + c + 4]) = hi;
  }
}

// ---------------- LDS-free MFMA bf16 GEMM core (BM=128, BN=256), bf16 out -----------
__device__ __forceinline__ void gemm_core(
    const bf16_t* __restrict__ A, const bf16_t* __restrict__ W0t,
    const bf16_t* __restrict__ B, const bf16_t* __restrict__ W1t,
    const float* __restrict__ bias, bf16_t* __restrict__ C, int rowBase) {
  const int tid = threadIdx.x;
  const int lane = tid & 63;
  const int wave = tid >> 6;
  const int lm = lane & 15;
  const int quad = lane >> 4;
  const int wm = (wave >> 1) * 64;
  const int wn = (wave & 1) * 128;

  f32x4 acc[4][8];
#pragma unroll
  for (int i = 0; i < 4; ++i)
#pragma unroll
    for (int j = 0; j < 8; ++j) acc[i][j] = (f32x4){0.f, 0.f, 0.f, 0.f};

#pragma unroll
  for (int phase = 0; phase < 2; ++phase) {
    const bf16_t* __restrict__ Ain = phase ? B : A;
    const bf16_t* __restrict__ Wt  = phase ? W1t : W0t;
    const bf16_t* ap[4];
    const bf16_t* bp[8];
#pragma unroll
    for (int i = 0; i < 4; ++i)
      ap[i] = Ain + (size_t)(rowBase + wm + i * 16 + lm) * 256 + quad * 8;
#pragma unroll
    for (int j = 0; j < 8; ++j)
      bp[j] = Wt + (size_t)(wn + j * 16 + lm) * 256 + quad * 8;
    for (int kt = 0; kt < 8; ++kt) {
      bf16x8 af[4], bfr[8];
#pragma unroll
      for (int i = 0; i < 4; ++i)
        af[i] = *reinterpret_cast<const bf16x8*>(ap[i] + kt * 32);
#pragma unroll
      for (int j = 0; j < 8; ++j)
        bfr[j] = *reinterpret_cast<const bf16x8*>(bp[j] + kt * 32);
#pragma unroll
      for (int i = 0; i < 4; ++i)
#pragma unroll
        for (int j = 0; j < 8; ++j)
          acc[i][j] = __builtin_amdgcn_mfma_f32_16x16x32_bf16(af[i], bfr[j], acc[i][j], 0, 0, 0);
    }
  }
  float bj[8];
#pragma unroll
  for (int j = 0; j < 8; ++j) bj[j] = bias[wn + j * 16 + lm];
#pragma unroll
  for (int i = 0; i < 4; ++i) {
#pragma unroll
    for (int j = 0; j < 8; ++j) {
      int col = wn + j * 16 + lm;
#pragma unroll
      for (int r = 0; r < 4; ++r) {
        int row = rowBase + wm + i * 16 + quad * 4 + r;
        C[(size_t)row * 256 + col] = f2bf(fmaxf(acc[i][j][r] + bj[j], 0.f));
      }
    }
  }
}

// pair-batched GEMM1: X1[slot] = relu(AGG@wr0_e + hb@wo0_e + br0_e), e = pe + slot
__global__ __launch_bounds__(256) void k_gemm1_b(
    const bf16_t* __restrict__ AGG, const bf16_t* __restrict__ hb,
    const bf16_t* __restrict__ WT, const float* __restrict__ b_rel,
    bf16_t* __restrict__ X1p, int pe) {
  int slot = blockIdx.y, e = pe + slot;
  gemm_core(AGG, WT + (size_t)(e * 2) * 65536,
            hb, WT + (size_t)(8 + e * 2) * 65536,
            b_rel + (size_t)(e * 2) * 256,
            X1p + (size_t)slot * M_PAD * 256, blockIdx.x * 128);
}

// pair-batched GEMM2 + fused head: X2 never materialized.
// X2 = relu(A1@wr1 + X1@wo1 + br1) held in f32 registers; epilogue computes
// P = X2@wro, Q = X2@wto (per-row 6+6) via LDS-staged head weights, lane-shuffle
// reduction over the 16 lanes sharing a row, cross-wave combine in LDS, and writes
// PQ[n*64 + e*16 + {0..5, 8..13}] directly.
__global__ __launch_bounds__(256) void k_gemm2h_b(
    const bf16_t* __restrict__ A1p, const bf16_t* __restrict__ X1p,
    const bf16_t* __restrict__ WT, const float* __restrict__ b_rel,
    const float* __restrict__ w_relo, const float* __restrict__ w_rooto,
    float* __restrict__ PQ, int pe) {
  __shared__ float wPQ[256][12];     // head weights: [col][P c0..5, Q c0..5]
  __shared__ float pqs[2][128][12];  // per-wn-half partials, each entry written once
  const int slot = blockIdx.y, e = pe + slot;
  const bf16_t* A = A1p + (size_t)slot * M_PAD * 256;
  const bf16_t* B = X1p + (size_t)slot * M_PAD * 256;
  const bf16_t* W0t = WT + (size_t)(e * 2 + 1) * 65536;
  const bf16_t* W1t = WT + (size_t)(8 + e * 2 + 1) * 65536;
  const float* bias = b_rel + (size_t)(e * 2 + 1) * 256;
  const float* wro = w_relo + (size_t)e * 256 * OUTD;
  const float* wto = w_rooto + (size_t)e * 256 * OUTD;
  const int tid = threadIdx.x;
  const int lane = tid & 63;
  const int wave = tid >> 6;
  const int lm = lane & 15;
  const int quad = lane >> 4;
  const int wm = (wave >> 1) * 64;
  const int wn = (wave & 1) * 128;
  const int rowBase = blockIdx.x * 128;

  // stage head weights while MFMA operands stream
  for (int i2 = tid; i2 < 1536; i2 += 256) {
    int col = i2 / 6, c = i2 % 6;
    wPQ[col][c] = wro[i2];
    wPQ[col][6 + c] = wto[i2];
  }

  f32x4 acc[4][8];
#pragma unroll
  for (int i = 0; i < 4; ++i)
#pragma unroll
    for (int j = 0; j < 8; ++j) acc[i][j] = (f32x4){0.f, 0.f, 0.f, 0.f};

#pragma unroll
  for (int phase = 0; phase < 2; ++phase) {
    const bf16_t* __restrict__ Ain = phase ? B : A;
    const bf16_t* __restrict__ Wt  = phase ? W1t : W0t;
    const bf16_t* ap[4];
    const bf16_t* bp[8];
#pragma unroll
    for (int i = 0; i < 4; ++i)
      ap[i] = Ain + (size_t)(rowBase + wm + i * 16 + lm) * 256 + quad * 8;
#pragma unroll
    for (int j = 0; j < 8; ++j)
      bp[j] = Wt + (size_t)(wn + j * 16 + lm) * 256 + quad * 8;
    for (int kt = 0; kt < 8; ++kt) {
      bf16x8 af[4], bfr[8];
#pragma unroll
      for (int i = 0; i < 4; ++i)
        af[i] = *reinterpret_cast<const bf16x8*>(ap[i] + kt * 32);
#pragma unroll
      for (int j = 0; j < 8; ++j)
        bfr[j] = *reinterpret_cast<const bf16x8*>(bp[j] + kt * 32);
#pragma unroll
      for (int i = 0; i < 4; ++i)
#pragma unroll
        for (int j = 0; j < 8; ++j)
          acc[i][j] = __builtin_amdgcn_mfma_f32_16x16x32_bf16(af[i], bfr[j], acc[i][j], 0, 0, 0);
    }
  }
  // X2 = relu(acc + bias) in-register (f32)
  float bj[8];
#pragma unroll
  for (int j = 0; j < 8; ++j) bj[j] = bias[wn + j * 16 + lm];
#pragma unroll
  for (int i = 0; i < 4; ++i)
#pragma unroll
    for (int j = 0; j < 8; ++j)
#pragma unroll
      for (int r = 0; r < 4; ++r)
        acc[i][j][r] = fmaxf(acc[i][j][r] + bj[j], 0.f);

  __syncthreads();   // wPQ staging complete
  // 12 c-passes: lane dots its 8 cols, reduce over lm (lanes sharing a row)
  for (int c = 0; c < 12; ++c) {
    float wreg[8];
#pragma unroll
    for (int j = 0; j < 8; ++j) wreg[j] = wPQ[wn + j * 16 + lm][c];
#pragma unroll
    for (int i = 0; i < 4; ++i) {
#pragma unroll
      for (int r = 0; r < 4; ++r) {
        float s = 0.f;
#pragma unroll
        for (int j = 0; j < 8; ++j) s = fmaf(acc[i][j][r], wreg[j], s);
        s += __shfl_xor(s, 1, 64);
        s += __shfl_xor(s, 2, 64);
        s += __shfl_xor(s, 4, 64);
        s += __shfl_xor(s, 8, 64);
        if (lm == 0) pqs[wave & 1][wm + i * 16 + quad * 4 + r][c] = s;
      }
    }
  }
  __syncthreads();
  for (int i2 = tid; i2 < 128 * 12; i2 += 256) {
    int row = i2 / 12, c = i2 % 12;
    int gr = rowBase + row;
    if (gr < N_NODES) {
      float v = pqs[0][row][c] + pqs[1][row][c];
      int off = (c < 6) ? c : (c + 2);   // Q block at +8
      PQ[(size_t)gr * 64 + e * 16 + off] = v;
    }
  }
}

// ---------------- CSR gather, bf16 in/out (f32 accumulate, unroll-2) ----------------
__device__ __forceinline__ void gather_core(
    const int* __restrict__ row_start, const int* __restrict__ csr_src,
    const bf16_t* __restrict__ X, bf16_t* __restrict__ Cout) {
  int tid = threadIdx.x;
  int r = blockIdx.x * 8 + (tid >> 5);
  int f = (tid & 31) * 8;
  int j0 = row_start[r], j1 = row_start[r + 1];
  float a[8] = {0.f, 0.f, 0.f, 0.f, 0.f, 0.f, 0.f, 0.f};
  int j = j0;
  for (; j + 1 < j1; j += 2) {
    int s0 = csr_src[j];
    int s1 = csr_src[j + 1];
    bf16x8 v0 = *reinterpret_cast<const bf16x8*>(&X[(size_t)s0 * 256 + f]);
    bf16x8 v1 = *reinterpret_cast<const bf16x8*>(&X[(size_t)s1 * 256 + f]);
#pragma unroll
    for (int t = 0; t < 8; ++t) a[t] += bf2f((unsigned short)v0[t]);
#pragma unroll
    for (int t = 0; t < 8; ++t) a[t] += bf2f((unsigned short)v1[t]);
  }
  if (j < j1) {
    int s = csr_src[j];
    bf16x8 v = *reinterpret_cast<const bf16x8*>(&X[(size_t)s * 256 + f]);
#pragma unroll
    for (int t = 0; t < 8; ++t) a[t] += bf2f((unsigned short)v[t]);
  }
  ushort4 lo = make_ushort4(f2bf(a[0]), f2bf(a[1]), f2bf(a[2]), f2bf(a[3]));
  ushort4 hi = make_ushort4(f2bf(a[4]), f2bf(a[5]), f2bf(a[6]), f2bf(a[7]));
  *reinterpret_cast<ushort4*>(&Cout[(size_t)r * 256 + f]) = lo;
  *reinterpret_cast<ushort4*>(&Cout[(size_t)r * 256 + f + 4]) = hi;
}

__global__ void k_gather(const int* __restrict__ row_start, const int* __restrict__ csr_src,
                         const bf16_t* __restrict__ X, bf16_t* __restrict__ Cout) {
  gather_core(row_start, csr_src, X, Cout);
}

__global__ void k_gather_b(const int* __restrict__ row_start, const int* __restrict__ csr_src,
                           const bf16_t* __restrict__ X1p, bf16_t* __restrict__ A1p) {
  size_t off = (size_t)blockIdx.y * M_PAD * 256;
  gather_core(row_start, csr_src, X1p + off, A1p + off);
}

// ---------------- numpy-faithful f32 router: LDS-free main loop (frozen r15) --------
__global__ __launch_bounds__(256) void k_router_np(
    const float* __restrict__ h, const int* __restrict__ batch,
    const float* __restrict__ gf, const float* __restrict__ lnn,
    const float* __restrict__ rtw1, const float* __restrict__ rtb1,
    const float* __restrict__ lng, const float* __restrict__ lnb,
    const float* __restrict__ rtw2, const float* __restrict__ rtb2,
    const float* __restrict__ centers, float* __restrict__ sw) {
  __shared__ float sr[4][128];
  __shared__ float sa[4][128];
  __shared__ float sb[4][8];
  const int tid = threadIdx.x;
  const int w = tid >> 6;
  const int l = tid & 63;
  const int nbase = blockIdx.x * 16 + w * 4;   // 3125*16 = 50000 exactly

  float hreg[4][4];
#pragma unroll
  for (int nn = 0; nn < 4; ++nn)
#pragma unroll
    for (int j = 0; j < 4; ++j)
      hreg[nn][j] = h[(size_t)(nbase + nn) * 256 + j * 64 + l];

  float acc0[4] = {0.f, 0.f, 0.f, 0.f};
  float acc1[4] = {0.f, 0.f, 0.f, 0.f};
#pragma unroll
  for (int j = 0; j < 4; ++j) {
#pragma unroll 16
    for (int k2 = 0; k2 < 64; ++k2) {
      int k = j * 64 + k2;
      float w0 = rtw1[k * RHD + l];
      float w1 = rtw1[k * RHD + l + 64];
#pragma unroll
      for (int nn = 0; nn < 4; ++nn) {
        float hv = readlane_f(hreg[nn][j], k2);
        acc0[nn] = __fmaf_rn(hv, w0, acc0[nn]);
        acc1[nn] = __fmaf_rn(hv, w1, acc1[nn]);
      }
    }
  }

  float g0a = rtw1[256 * RHD + l],      g1a = rtw1[257 * RHD + l];
  float g0b = rtw1[256 * RHD + l + 64], g1b = rtw1[257 * RHD + l + 64];
  float b0 = rtb1[l], b1v = rtb1[l + 64];
  float lga = lng[l], lgb = lng[l + 64];
  float lba = lnb[l], lbb = lnb[l + 64];

  for (int nn = 0; nn < 4; ++nn) {
    int node = nbase + nn;
    int g = batch[node];
    float gf0 = gf[g * 2 + 0], gf1 = gf[g * 2 + 1], nl = lnn[g];
    float t0 = acc0[nn], t1 = acc1[nn];
    t0 = __fmaf_rn(gf0, g0a, t0);
    t0 = __fmaf_rn(gf1, g1a, t0);
    t1 = __fmaf_rn(gf0, g0b, t1);
    t1 = __fmaf_rn(gf1, g1b, t1);
    float r0 = __fadd_rn(t0, b0);
    float r1 = __fadd_rn(t1, b1v);
    __syncthreads();
    sr[w][l] = r0; sr[w][l + 64] = r1;
    __syncthreads();

    float aj = 0.f;
    if (l < 8) {
      aj = sr[w][l];
      for (int i = 8; i < 128; i += 8) aj = __fadd_rn(aj, sr[w][i + l]);
    }
    {
      float a0 = __shfl(aj, 0, 64), a1 = __shfl(aj, 1, 64);
      float a2 = __shfl(aj, 2, 64), a3 = __shfl(aj, 3, 64);
      float a4 = __shfl(aj, 4, 64), a5 = __shfl(aj, 5, 64);
      float a6 = __shfl(aj, 6, 64), a7 = __shfl(aj, 7, 64);
      float s01 = __fadd_rn(a0, a1), s23 = __fadd_rn(a2, a3);
      float s45 = __fadd_rn(a4, a5), s67 = __fadd_rn(a6, a7);
      aj = __fadd_rn(__fadd_rn(s01, s23), __fadd_rn(s45, s67));
    }
    float mu = __fdiv_rn(aj, 128.0f);
    float d0 = __fsub_rn(r0, mu), d1 = __fsub_rn(r1, mu);
    sr[w][l] = __fmul_rn(d0, d0);
    sr[w][l + 64] = __fmul_rn(d1, d1);
    __syncthreads();
    float qj = 0.f;
    if (l < 8) {
      qj = sr[w][l];
      for (int i = 8; i < 128; i += 8) qj = __fadd_rn(qj, sr[w][i + l]);
    }
    {
      float a0 = __shfl(qj, 0, 64), a1 = __shfl(qj, 1, 64);
      float a2 = __shfl(qj, 2, 64), a3 = __shfl(qj, 3, 64);
      float a4 = __shfl(qj, 4, 64), a5 = __shfl(qj, 5, 64);
      float a6 = __shfl(qj, 6, 64), a7 = __shfl(qj, 7, 64);
      float s01 = __fadd_rn(a0, a1), s23 = __fadd_rn(a2, a3);
      float s45 = __fadd_rn(a4, a5), s67 = __fadd_rn(a6, a7);
      qj = __fadd_rn(__fadd_rn(s01, s23), __fadd_rn(s45, s67));
    }
    float var = __fdiv_rn(qj, 128.0f);
    float inv = __fdiv_rn(1.0f, sqrtf(__fadd_rn(var, 1e-5f)));
    float y0 = __fadd_rn(__fmul_rn(__fmul_rn(d0, inv), lga), lba);
    float y1 = __fadd_rn(__fmul_rn(__fmul_rn(d1, inv), lgb), lbb);
    sa[w][l] = fmaxf(y0, 0.f);
    sa[w][l + 64] = fmaxf(y1, 0.f);
    __syncthreads();

    if (l < 4) {
      float acc = 0.f;
      for (int k = 0; k < 128; ++k) acc = __fmaf_rn(sa[w][k], rtw2[k * 4 + l], acc);
      float lrn = __fadd_rn(acc, rtb2[l]);
      float dd = __fsub_rn(nl, centers[l]);
      float pr = -__fmul_rn(dd, dd);
      sb[w][4 + l] = __fadd_rn(__fmul_rn(0.65f, lrn), __fmul_rn(0.35f, pr));
    }
    __syncthreads();

    if (l == 0) {
      float lg[4] = {sb[w][4], sb[w][5], sb[w][6], sb[w][7]};
      float mx = fmaxf(fmaxf(lg[0], lg[1]), fmaxf(lg[2], lg[3]));
      float e[4];
#pragma unroll
      for (int c = 0; c < 4; ++c)
        e[c] = (float)exp((double)__fsub_rn(lg[c], mx));
      float S = __fadd_rn(__fadd_rn(__fadd_rn(e[0], e[1]), e[2]), e[3]);
      float p[4];
#pragma unroll
      for (int c = 0; c < 4; ++c) p[c] = __fdiv_rn(e[c], S);
      int i1 = 0;
#pragma unroll
      for (int c = 1; c < 4; ++c) if (p[c] > p[i1]) i1 = c;
      int i2 = -1;
#pragma unroll
      for (int c = 0; c < 4; ++c) {
        if (c == i1) continue;
        if (i2 < 0 || p[c] > p[i2]) i2 = c;
      }
      float den = __fadd_rn(__fadd_rn(p[i1], p[i2]), 1e-8f);
      float swv[4] = {0.f, 0.f, 0.f, 0.f};
      swv[i1] = __fdiv_rn(p[i1], den);
      swv[i2] = __fdiv_rn(p[i2], den);
      *reinterpret_cast<float4*>(&sw[node * 4]) =
          make_float4(swv[0], swv[1], swv[2], swv[3]);
    }
  }
}

// ---------------- head stage 2 (all experts, single kernel) -------------------------
__global__ void k_headfin_all(const int* __restrict__ row_start,
                              const int* __restrict__ csr_src,
                              const float* __restrict__ PQ, const float* __restrict__ b_relo,
                              const float* __restrict__ sw, float* __restrict__ out) {
  int t = blockIdx.x * 256 + threadIdx.x;
  int n = t >> 3, c = t & 7;
  if (n >= N_NODES || c >= 6) return;
  int j0 = row_start[n], j1 = row_start[n + 1];
  float av0 = 0.f, av1 = 0.f, av2 = 0.f, av3 = 0.f;
  for (int j = j0; j < j1; ++j) {
    size_t base = (size_t)csr_src[j] * 64 + c;
    av0 += PQ[base];
    av1 += PQ[base + 16];
    av2 += PQ[base + 32];
    av3 += PQ[base + 48];
  }
  float4 s4 = *reinterpret_cast<const float4*>(&sw[n * 4]);
  size_t nb = (size_t)n * 64 + c;
  float v = s4.x * (av0 + b_relo[0 * 6 + c] + PQ[nb + 8]);
  v += s4.y * (av1 + b_relo[1 * 6 + c] + PQ[nb + 16 + 8]);
  v += s4.z * (av2 + b_relo[2 * 6 + c] + PQ[nb + 32 + 8]);
  v += s4.w * (av3 + b_relo[3 * 6 + c] + PQ[nb + 48 + 8]);
  out[n * 6 + c] = v;
}

// ---------------- launch ----------------
extern "C" void kernel_launch(void* const* d_in, const int* in_sizes, int n_in,
                              void* d_out, int out_size, void* d_ws, size_t ws_size,
                              hipStream_t stream) {
  const float* x        = (const float*)d_in[0];
  const int*   edge     = (const int*)d_in[1];
  const int*   batch    = (const int*)d_in[2];
  const float* enc_w1   = (const float*)d_in[4];
  const float* enc_b1   = (const float*)d_in[5];
  const float* enc_w2   = (const float*)d_in[6];
  const float* enc_b2   = (const float*)d_in[7];
  const float* rt_w1    = (const float*)d_in[8];
  const float* rt_b1    = (const float*)d_in[9];
  const float* ln_g     = (const float*)d_in[10];
  const float* ln_b     = (const float*)d_in[11];
  const float* rt_w2    = (const float*)d_in[12];
  const float* rt_b2    = (const float*)d_in[13];
  const float* centers  = (const float*)d_in[14];
  const float* w_rel    = (const float*)d_in[15];
  const float* b_rel    = (const float*)d_in[16];
  const float* w_root   = (const float*)d_in[17];
  const float* w_relo   = (const float*)d_in[18];
  const float* b_relo   = (const float*)d_in[19];
  const float* w_rooto  = (const float*)d_in[20];
  float* out = (float*)d_out;

  char* wsp = (char*)d_ws;
  auto alloc = [&](size_t bytes) -> char* {
    char* p = wsp;
    wsp += (bytes + 255) & ~(size_t)255;
    return p;
  };
  const size_t actF32 = (size_t)M_PAD * 256 * sizeof(float);    // 51.25 MB
  const size_t actB16 = (size_t)M_PAD * 256 * sizeof(bf16_t);   // 25.63 MB
  char*   hx  = alloc(actF32);    // h; doubles as X1 pair after router
  float*  h   = (float*)hx;
  bf16_t* X1p = (bf16_t*)hx;
  char*   tx  = alloc(actF32);    // t; doubles as A1 pair after encoder GEMM
  float*  t   = (float*)tx;
  bf16_t* A1p = (bf16_t*)tx;
  bf16_t* hb  = (bf16_t*)alloc(actB16);
  bf16_t* AGG = (bf16_t*)alloc(actB16);
  bf16_t* WT  = (bf16_t*)alloc((size_t)16 * 65536 * sizeof(bf16_t));
  float* PQ   = (float*)alloc((size_t)N_NODES * 64 * sizeof(float));   // 12.8 MB
  float* swp  = (float*)alloc((size_t)N_NODES * 4 * sizeof(float));
  int*   n_cnt = (int*)alloc(NG * sizeof(int));
  int*   e_cnt = (int*)alloc(NG * sizeof(int));
  float* gfbuf = (float*)alloc(NG * 2 * sizeof(float));
  float* lnn   = (float*)alloc(NG * sizeof(float));
  int* deg       = (int*)alloc((size_t)N_NODES * sizeof(int));
  int* row_start = (int*)alloc((size_t)(N_NODES + 1) * sizeof(int));
  int* cursor    = (int*)alloc((size_t)N_NODES * sizeof(int));
  int* csr_src   = (int*)alloc((size_t)NUM_EDGES * sizeof(int));

  // graph stats + CSR build + weight prep
  k_zero<<<(N_NODES + 255) / 256, 256, 0, stream>>>(deg, n_cnt, e_cnt);
  k_count_nodes<<<(N_NODES + 255) / 256, 256, 0, stream>>>(batch, n_cnt);
  k_count_edges<<<(NUM_EDGES + 255) / 256, 256, 0, stream>>>(edge, batch, e_cnt, deg);
  k_graph_stats<<<1, 64, 0, stream>>>(n_cnt, e_cnt, gfbuf, lnn);
  k_scan<<<1, 1024, 0, stream>>>(deg, row_start, cursor);
  k_fill<<<(NUM_EDGES + 255) / 256, 256, 0, stream>>>(edge, cursor, csr_src);
  dim3 wgrid(16, 4);
  k_wprep<<<wgrid, 256, 0, stream>>>(w_rel, w_root, WT);

  // encoder (frozen math; epilogue also writes hb)
  k_enc1<<<(N_NODES + 15) / 16, 256, 0, stream>>>(x, enc_w1, enc_b1, t);
  dim3 egrid(M_PAD / 128, 2);
  k_gemm_enc<<<egrid, 256, 0, stream>>>(t, enc_w2, enc_b2, h, hb, N_NODES);

  // router (LDS-free main loop; bit-identical arithmetic)
  k_router_np<<<N_NODES / 16, 256, 0, stream>>>(
      h, batch, gfbuf, lnn, rt_w1, rt_b1, ln_g, ln_b, rt_w2, rt_b2, centers, swp);

  // loop-invariant agg_h (after router: X1p will overwrite h)
  k_gather<<<N_NODES / 8, 256, 0, stream>>>(row_start, csr_src, hb, AGG);

  // experts, pair-batched (gridDim.y = 2); GEMM2 fused with head projection
  dim3 ggrid(M_PAD / 128, 2);
  dim3 grid_gather(N_NODES / 8, 2);
  for (int pe = 0; pe < NEXP; pe += 2) {
    k_gemm1_b<<<ggrid, 256, 0, stream>>>(AGG, hb, WT, b_rel, X1p, pe);
    k_gather_b<<<grid_gather, 256, 0, stream>>>(row_start, csr_src, X1p, A1p);
    k_gemm2h_b<<<ggrid, 256, 0, stream>>>(A1p, X1p, WT, b_rel, w_relo, w_rooto, PQ, pe);
  }
  k_headfin_all<<<(N_NODES * 8 + 255) / 256, 256, 0, stream>>>(
      row_start, csr_src, PQ, b_relo, swp, out);
}

// Round 17
// 1389.578 us; speedup vs baseline: 1.0712x; 1.0712x over previous
//
#include <hip/hip_runtime.h>
#include <math.h>

#define N_NODES 50000
#define M_PAD 50048            // 391 * 128
#define NUM_EDGES 800000
#define NG 8
#define HID 256
#define RHD 128
#define NEXP 4
#define OUTD 6

typedef unsigned short bf16_t;
using f32x4  = __attribute__((ext_vector_type(4))) float;
using bf16x8 = __attribute__((ext_vector_type(8))) short;

__device__ __forceinline__ float bf2f(unsigned short u) {
  union { unsigned int i; float f; } v; v.i = ((unsigned int)u) << 16; return v.f;
}
__device__ __forceinline__ unsigned short f2bf(float f) {
  union { float f; unsigned int i; } v; v.f = f;
  unsigned int x = v.i;
  unsigned int r = x + 0x7fffu + ((x >> 16) & 1u);  // RNE
  return (unsigned short)(r >> 16);
}
__device__ __forceinline__ float readlane_f(float v, int lane) {
  return __int_as_float(__builtin_amdgcn_readlane(__float_as_int(v), lane));
}

// ---------------- zero init ----------------
__global__ void k_zero(int* __restrict__ deg, int* __restrict__ n_cnt,
                       int* __restrict__ e_cnt) {
  int i = blockIdx.x * blockDim.x + threadIdx.x;
  if (i < N_NODES) deg[i] = 0;
  if (i < NG) { n_cnt[i] = 0; e_cnt[i] = 0; }
}

// ---------------- graph stats ----------------
__global__ void k_count_nodes(const int* __restrict__ batch, int* __restrict__ n_cnt) {
  __shared__ int hist[NG];
  int t = threadIdx.x;
  if (t < NG) hist[t] = 0;
  __syncthreads();
  int i = blockIdx.x * blockDim.x + t;
  if (i < N_NODES) atomicAdd(&hist[batch[i]], 1);
  __syncthreads();
  if (t < NG && hist[t]) atomicAdd(&n_cnt[t], hist[t]);
}

__global__ void k_count_edges(const int* __restrict__ edge, const int* __restrict__ batch,
                              int* __restrict__ e_cnt, int* __restrict__ deg) {
  __shared__ int hist[NG];
  int t = threadIdx.x;
  if (t < NG) hist[t] = 0;
  __syncthreads();
  int i = blockIdx.x * blockDim.x + t;
  if (i < NUM_EDGES) {
    int s = edge[i];
    int d = edge[NUM_EDGES + i];
    atomicAdd(&hist[batch[s]], 1);
    atomicAdd(&deg[d], 1);
  }
  __syncthreads();
  if (t < NG && hist[t]) atomicAdd(&e_cnt[t], hist[t]);
}

// numpy-faithful f32 stats (frozen: razor-sensitive)
__device__ __forceinline__ float tree8(const float* v) {
  float s01 = __fadd_rn(v[0], v[1]);
  float s23 = __fadd_rn(v[2], v[3]);
  float s45 = __fadd_rn(v[4], v[5]);
  float s67 = __fadd_rn(v[6], v[7]);
  return __fadd_rn(__fadd_rn(s01, s23), __fadd_rn(s45, s67));
}

__global__ void k_graph_stats(const int* __restrict__ n_cnt, const int* __restrict__ e_cnt,
                              float* __restrict__ gf, float* __restrict__ lnn) {
  if (threadIdx.x != 0 || blockIdx.x != 0) return;
  float logn[NG], loge[NG];
  for (int g = 0; g < NG; ++g) {
    float nf = fmaxf((float)n_cnt[g], 1.0f);
    logn[g] = (float)log((double)nf);
    float ef = fmaxf((float)e_cnt[g], 0.0f);
    loge[g] = (float)log1p((double)ef);
  }
  float m0 = __fdiv_rn(tree8(logn), 8.0f);
  float m1 = __fdiv_rn(tree8(loge), 8.0f);
  float sq0[NG], sq1[NG];
  float mn = 3.0e38f, mx = -3.0e38f;
  for (int g = 0; g < NG; ++g) {
    float d0 = __fsub_rn(logn[g], m0);
    float d1 = __fsub_rn(loge[g], m1);
    sq0[g] = __fmul_rn(d0, d0);
    sq1[g] = __fmul_rn(d1, d1);
    mn = fminf(mn, logn[g]); mx = fmaxf(mx, logn[g]);
  }
  float s0 = __fadd_rn(sqrtf(__fdiv_rn(tree8(sq0), 8.0f)), 1e-6f);
  float s1 = __fadd_rn(sqrtf(__fdiv_rn(tree8(sq1), 8.0f)), 1e-6f);
  float denom = __fadd_rn(__fsub_rn(mx, mn), 1e-6f);
  for (int g = 0; g < NG; ++g) {
    gf[g * 2 + 0] = __fdiv_rn(__fsub_rn(logn[g], m0), s0);
    gf[g * 2 + 1] = __fdiv_rn(__fsub_rn(loge[g], m1), s1);
    lnn[g] = __fdiv_rn(__fsub_rn(logn[g], mn), denom);
  }
}

// ---------------- CSR build ----------------
__global__ void k_scan(const int* __restrict__ deg, int* __restrict__ row_start,
                       int* __restrict__ cursor) {
  __shared__ int temp[1024];
  int tid = threadIdx.x;
  int carry = 0;
  for (int base = 0; base < N_NODES; base += 1024) {
    int i = base + tid;
    int v = (i < N_NODES) ? deg[i] : 0;
    temp[tid] = v;
    __syncthreads();
    for (int off = 1; off < 1024; off <<= 1) {
      int t = (tid >= off) ? temp[tid - off] : 0;
      __syncthreads();
      temp[tid] += t;
      __syncthreads();
    }
    int incl = temp[tid];
    if (i < N_NODES) {
      int e = carry + incl - v;
      row_start[i] = e;
      cursor[i] = e;
    }
    carry += temp[1023];
    __syncthreads();
  }
  if (tid == 0) row_start[N_NODES] = carry;
}

__global__ void k_fill(const int* __restrict__ edge, int* __restrict__ cursor,
                       int* __restrict__ csr_src) {
  int i = blockIdx.x * blockDim.x + threadIdx.x;
  if (i < NUM_EDGES) {
    int d = edge[NUM_EDGES + i];
    int p = atomicAdd(&cursor[d], 1);
    csr_src[p] = edge[i];
  }
}

// ---------------- encoder layer 1 (frozen) -----------------------------------------
__global__ void k_enc1(const float* __restrict__ x, const float* __restrict__ w1,
                       const float* __restrict__ b1, float* __restrict__ t) {
  __shared__ float W[6 * 256];
  __shared__ float xs[16][6];
  int tid = threadIdx.x;
  for (int i = tid; i < 6 * 256; i += 256) W[i] = w1[i];
  int base = blockIdx.x * 16;
  if (tid < 96) {
    int n = tid / 6, k = tid % 6;
    int node = base + n;
    xs[n][k] = (node < N_NODES) ? x[node * 16 + 4 + k] : 0.f;
  }
  __syncthreads();
  float b = b1[tid];
  for (int n = 0; n < 16; ++n) {
    int node = base + n;
    if (node >= N_NODES) break;
    float acc = 0.f;
#pragma unroll
    for (int k = 0; k < 6; ++k) acc = __fmaf_rn(xs[n][k], W[k * 256 + tid], acc);
    t[node * 256 + tid] = fmaxf(__fadd_rn(acc, b), 0.f);
  }
}

// ---------------- fp32 SIMT GEMM (frozen math; epilogue also emits bf16 copy) -------
__global__ __launch_bounds__(256, 2) void k_gemm_enc(
    const float* __restrict__ A, const float* __restrict__ W0,
    const float* __restrict__ bias, float* __restrict__ C,
    bf16_t* __restrict__ Cb, int M) {
  __shared__ float As[16][132];
  __shared__ float Ws[16][128];
  const int tid = threadIdx.x;
  const int tx = tid & 15;
  const int ty = tid >> 4;
  const int rowBase = blockIdx.x * 128;
  const int colBase = blockIdx.y * 128;

  float acc[2][2][4][4];
#pragma unroll
  for (int a = 0; a < 2; ++a)
#pragma unroll
    for (int b = 0; b < 2; ++b)
#pragma unroll
      for (int i = 0; i < 4; ++i)
#pragma unroll
        for (int j = 0; j < 4; ++j) acc[a][b][i][j] = 0.f;

  for (int kt = 0; kt < 16; ++kt) {
    const int kb = kt * 16;
#pragma unroll
    for (int l = 0; l < 2; ++l) {
      int idx = tid + l * 256;
      int m = idx >> 2;
      int kq = (idx & 3) * 4;
      int arow = rowBase + m;
      float4 av = make_float4(0.f, 0.f, 0.f, 0.f);
      if (arow < M) av = *reinterpret_cast<const float4*>(&A[arow * 256 + kb + kq]);
      As[kq + 0][m] = av.x; As[kq + 1][m] = av.y;
      As[kq + 2][m] = av.z; As[kq + 3][m] = av.w;
    }
#pragma unroll
    for (int l = 0; l < 2; ++l) {
      int idx = tid + l * 256;
      int k = idx >> 5;
      int nq = (idx & 31) * 4;
      float4 wv = *reinterpret_cast<const float4*>(&W0[(kb + k) * 256 + colBase + nq]);
      *reinterpret_cast<float4*>(&Ws[k][nq]) = wv;
    }
    __syncthreads();
#pragma unroll
    for (int k = 0; k < 16; ++k) {
      float4 a0 = *reinterpret_cast<const float4*>(&As[k][ty * 4]);
      float4 a1 = *reinterpret_cast<const float4*>(&As[k][64 + ty * 4]);
      float4 w0 = *reinterpret_cast<const float4*>(&Ws[k][tx * 4]);
      float4 w1 = *reinterpret_cast<const float4*>(&Ws[k][64 + tx * 4]);
      float ar[2][4] = {{a0.x, a0.y, a0.z, a0.w}, {a1.x, a1.y, a1.z, a1.w}};
      float wr[2][4] = {{w0.x, w0.y, w0.z, w0.w}, {w1.x, w1.y, w1.z, w1.w}};
#pragma unroll
      for (int ri = 0; ri < 2; ++ri)
#pragma unroll
        for (int i = 0; i < 4; ++i)
#pragma unroll
          for (int ci = 0; ci < 2; ++ci)
#pragma unroll
            for (int j = 0; j < 4; ++j)
              acc[ri][ci][i][j] = __fmaf_rn(ar[ri][i], wr[ci][j], acc[ri][ci][i][j]);
    }
    __syncthreads();
  }
  float4 bv0 = *reinterpret_cast<const float4*>(&bias[colBase + tx * 4]);
  float4 bv1 = *reinterpret_cast<const float4*>(&bias[colBase + 64 + tx * 4]);
  float bb[2][4] = {{bv0.x, bv0.y, bv0.z, bv0.w}, {bv1.x, bv1.y, bv1.z, bv1.w}};
#pragma unroll
  for (int ri = 0; ri < 2; ++ri) {
#pragma unroll
    for (int i = 0; i < 4; ++i) {
      int row = rowBase + ri * 64 + ty * 4 + i;
      if (row < M) {
#pragma unroll
        for (int ci = 0; ci < 2; ++ci) {
          float o[4];
#pragma unroll
          for (int j = 0; j < 4; ++j)
            o[j] = __fadd_rn(acc[ri][ci][i][j], bb[ci][j]);
          *reinterpret_cast<float4*>(&C[row * 256 + colBase + ci * 64 + tx * 4]) =
              make_float4(o[0], o[1], o[2], o[3]);
          ushort4 ob = make_ushort4(f2bf(o[0]), f2bf(o[1]), f2bf(o[2]), f2bf(o[3]));
          *reinterpret_cast<ushort4*>(&Cb[(size_t)row * 256 + colBase + ci * 64 + tx * 4]) = ob;
        }
      }
    }
  }
}

// ---------------- weight prep: transpose f32 [k][n] -> bf16 [n][k] ------------------
__global__ void k_wprep(const float* __restrict__ w_rel, const float* __restrict__ w_root,
                        bf16_t* __restrict__ WT) {
  __shared__ bf16_t tile[64][258];
  int m = blockIdx.x;
  int k0 = blockIdx.y * 64;
  const float* src = (m < 8) ? (w_rel + (size_t)m * 65536)
                             : (w_root + (size_t)(m - 8) * 65536);
  bf16_t* dst = WT + (size_t)m * 65536;
  int tid = threadIdx.x;
  for (int r = 0; r < 64; ++r)
    tile[r][tid] = f2bf(src[(k0 + r) * 256 + tid]);
  __syncthreads();
  for (int c = 0; c < 64; c += 8) {
    ushort4 lo, hi;
    lo.x = tile[c + 0][tid]; lo.y = tile[c + 1][tid];
    lo.z = tile[c + 2][tid]; lo.w = tile[c + 3][tid];
    hi.x = tile[c + 4][tid]; hi.y = tile[c + 5][tid];
    hi.z = tile[c + 6][tid]; hi.w = tile[c + 7][tid];
    *reinterpret_cast<ushort4*>(&dst[tid * 256 + k0 + c]) = lo;
    *reinterpret_cast<ushort4*>(&dst[tid * 256 + k0 + c + 4]) = hi;
  }
}

// ---------------- LDS-free MFMA bf16 GEMM core (BM=128, BN=256), bf16 out -----------
__device__ __forceinline__ void gemm_core(
    const bf16_t* __restrict__ A, const bf16_t* __restrict__ W0t,
    const bf16_t* __restrict__ B, const bf16_t* __restrict__ W1t,
    const float* __restrict__ bias, bf16_t* __restrict__ C, int rowBase) {
  const int tid = threadIdx.x;
  const int lane = tid & 63;
  const int wave = tid >> 6;
  const int lm = lane & 15;
  const int quad = lane >> 4;
  const int wm = (wave >> 1) * 64;
  const int wn = (wave & 1) * 128;

  f32x4 acc[4][8];
#pragma unroll
  for (int i = 0; i < 4; ++i)
#pragma unroll
    for (int j = 0; j < 8; ++j) acc[i][j] = (f32x4){0.f, 0.f, 0.f, 0.f};

#pragma unroll
  for (int phase = 0; phase < 2; ++phase) {
    const bf16_t* __restrict__ Ain = phase ? B : A;
    const bf16_t* __restrict__ Wt  = phase ? W1t : W0t;
    const bf16_t* ap[4];
    const bf16_t* bp[8];
#pragma unroll
    for (int i = 0; i < 4; ++i)
      ap[i] = Ain + (size_t)(rowBase + wm + i * 16 + lm) * 256 + quad * 8;
#pragma unroll
    for (int j = 0; j < 8; ++j)
      bp[j] = Wt + (size_t)(wn + j * 16 + lm) * 256 + quad * 8;
    for (int kt = 0; kt < 8; ++kt) {
      bf16x8 af[4], bfr[8];
#pragma unroll
      for (int i = 0; i < 4; ++i)
        af[i] = *reinterpret_cast<const bf16x8*>(ap[i] + kt * 32);
#pragma unroll
      for (int j = 0; j < 8; ++j)
        bfr[j] = *reinterpret_cast<const bf16x8*>(bp[j] + kt * 32);
#pragma unroll
      for (int i = 0; i < 4; ++i)
#pragma unroll
        for (int j = 0; j < 8; ++j)
          acc[i][j] = __builtin_amdgcn_mfma_f32_16x16x32_bf16(af[i], bfr[j], acc[i][j], 0, 0, 0);
    }
  }
  float bj[8];
#pragma unroll
  for (int j = 0; j < 8; ++j) bj[j] = bias[wn + j * 16 + lm];
#pragma unroll
  for (int i = 0; i < 4; ++i) {
#pragma unroll
    for (int j = 0; j < 8; ++j) {
      int col = wn + j * 16 + lm;
#pragma unroll
      for (int r = 0; r < 4; ++r) {
        int row = rowBase + wm + i * 16 + quad * 4 + r;
        C[(size_t)row * 256 + col] = f2bf(fmaxf(acc[i][j][r] + bj[j], 0.f));
      }
    }
  }
}

// pair-batched GEMM1: X1[slot] = relu(AGG@wr0_e + hb@wo0_e + br0_e), e = pe + slot
__global__ __launch_bounds__(256) void k_gemm1_b(
    const bf16_t* __restrict__ AGG, const bf16_t* __restrict__ hb,
    const bf16_t* __restrict__ WT, const float* __restrict__ b_rel,
    bf16_t* __restrict__ X1p, int pe) {
  int slot = blockIdx.y, e = pe + slot;
  gemm_core(AGG, WT + (size_t)(e * 2) * 65536,
            hb, WT + (size_t)(8 + e * 2) * 65536,
            b_rel + (size_t)(e * 2) * 256,
            X1p + (size_t)slot * M_PAD * 256, blockIdx.x * 128);
}

// pair-batched GEMM2 (in-place): X2[slot] = relu(A1[slot]@wr1_e + X1[slot]@wo1_e + br1_e)
__global__ __launch_bounds__(256) void k_gemm2_b(
    const bf16_t* __restrict__ A1p, bf16_t* __restrict__ X1p,
    const bf16_t* __restrict__ WT, const float* __restrict__ b_rel, int pe) {
  int slot = blockIdx.y, e = pe + slot;
  bf16_t* Xs = X1p + (size_t)slot * M_PAD * 256;
  gemm_core(A1p + (size_t)slot * M_PAD * 256, WT + (size_t)(e * 2 + 1) * 65536,
            Xs, WT + (size_t)(8 + e * 2 + 1) * 65536,
            b_rel + (size_t)(e * 2 + 1) * 256, Xs, blockIdx.x * 128);
}

// ---------------- CSR gather, bf16 in/out (f32 accumulate, unroll-2) ----------------
__device__ __forceinline__ void gather_core(
    const int* __restrict__ row_start, const int* __restrict__ csr_src,
    const bf16_t* __restrict__ X, bf16_t* __restrict__ Cout) {
  int tid = threadIdx.x;
  int r = blockIdx.x * 8 + (tid >> 5);
  int f = (tid & 31) * 8;
  int j0 = row_start[r], j1 = row_start[r + 1];
  float a[8] = {0.f, 0.f, 0.f, 0.f, 0.f, 0.f, 0.f, 0.f};
  int j = j0;
  for (; j + 1 < j1; j += 2) {
    int s0 = csr_src[j];
    int s1 = csr_src[j + 1];
    bf16x8 v0 = *reinterpret_cast<const bf16x8*>(&X[(size_t)s0 * 256 + f]);
    bf16x8 v1 = *reinterpret_cast<const bf16x8*>(&X[(size_t)s1 * 256 + f]);
#pragma unroll
    for (int t = 0; t < 8; ++t) a[t] += bf2f((unsigned short)v0[t]);
#pragma unroll
    for (int t = 0; t < 8; ++t) a[t] += bf2f((unsigned short)v1[t]);
  }
  if (j < j1) {
    int s = csr_src[j];
    bf16x8 v = *reinterpret_cast<const bf16x8*>(&X[(size_t)s * 256 + f]);
#pragma unroll
    for (int t = 0; t < 8; ++t) a[t] += bf2f((unsigned short)v[t]);
  }
  ushort4 lo = make_ushort4(f2bf(a[0]), f2bf(a[1]), f2bf(a[2]), f2bf(a[3]));
  ushort4 hi = make_ushort4(f2bf(a[4]), f2bf(a[5]), f2bf(a[6]), f2bf(a[7]));
  *reinterpret_cast<ushort4*>(&Cout[(size_t)r * 256 + f]) = lo;
  *reinterpret_cast<ushort4*>(&Cout[(size_t)r * 256 + f + 4]) = hi;
}

__global__ void k_gather(const int* __restrict__ row_start, const int* __restrict__ csr_src,
                         const bf16_t* __restrict__ X, bf16_t* __restrict__ Cout) {
  gather_core(row_start, csr_src, X, Cout);
}

__global__ void k_gather_b(const int* __restrict__ row_start, const int* __restrict__ csr_src,
                           const bf16_t* __restrict__ X1p, bf16_t* __restrict__ A1p) {
  size_t off = (size_t)blockIdx.y * M_PAD * 256;
  gather_core(row_start, csr_src, X1p + off, A1p + off);
}

// ---------------- numpy-faithful f32 router: LDS-free main loop (frozen r15) --------
__global__ __launch_bounds__(256) void k_router_np(
    const float* __restrict__ h, const int* __restrict__ batch,
    const float* __restrict__ gf, const float* __restrict__ lnn,
    const float* __restrict__ rtw1, const float* __restrict__ rtb1,
    const float* __restrict__ lng, const float* __restrict__ lnb,
    const float* __restrict__ rtw2, const float* __restrict__ rtb2,
    const float* __restrict__ centers, float* __restrict__ sw) {
  __shared__ float sr[4][128];
  __shared__ float sa[4][128];
  __shared__ float sb[4][8];
  const int tid = threadIdx.x;
  const int w = tid >> 6;
  const int l = tid & 63;
  const int nbase = blockIdx.x * 16 + w * 4;   // 3125*16 = 50000 exactly

  float hreg[4][4];
#pragma unroll
  for (int nn = 0; nn < 4; ++nn)
#pragma unroll
    for (int j = 0; j < 4; ++j)
      hreg[nn][j] = h[(size_t)(nbase + nn) * 256 + j * 64 + l];

  float acc0[4] = {0.f, 0.f, 0.f, 0.f};
  float acc1[4] = {0.f, 0.f, 0.f, 0.f};
#pragma unroll
  for (int j = 0; j < 4; ++j) {
#pragma unroll 16
    for (int k2 = 0; k2 < 64; ++k2) {
      int k = j * 64 + k2;
      float w0 = rtw1[k * RHD + l];
      float w1 = rtw1[k * RHD + l + 64];
#pragma unroll
      for (int nn = 0; nn < 4; ++nn) {
        float hv = readlane_f(hreg[nn][j], k2);
        acc0[nn] = __fmaf_rn(hv, w0, acc0[nn]);
        acc1[nn] = __fmaf_rn(hv, w1, acc1[nn]);
      }
    }
  }

  float g0a = rtw1[256 * RHD + l],      g1a = rtw1[257 * RHD + l];
  float g0b = rtw1[256 * RHD + l + 64], g1b = rtw1[257 * RHD + l + 64];
  float b0 = rtb1[l], b1v = rtb1[l + 64];
  float lga = lng[l], lgb = lng[l + 64];
  float lba = lnb[l], lbb = lnb[l + 64];

  for (int nn = 0; nn < 4; ++nn) {
    int node = nbase + nn;
    int g = batch[node];
    float gf0 = gf[g * 2 + 0], gf1 = gf[g * 2 + 1], nl = lnn[g];
    float t0 = acc0[nn], t1 = acc1[nn];
    t0 = __fmaf_rn(gf0, g0a, t0);
    t0 = __fmaf_rn(gf1, g1a, t0);
    t1 = __fmaf_rn(gf0, g0b, t1);
    t1 = __fmaf_rn(gf1, g1b, t1);
    float r0 = __fadd_rn(t0, b0);
    float r1 = __fadd_rn(t1, b1v);
    __syncthreads();
    sr[w][l] = r0; sr[w][l + 64] = r1;
    __syncthreads();

    float aj = 0.f;
    if (l < 8) {
      aj = sr[w][l];
      for (int i = 8; i < 128; i += 8) aj = __fadd_rn(aj, sr[w][i + l]);
    }
    {
      float a0 = __shfl(aj, 0, 64), a1 = __shfl(aj, 1, 64);
      float a2 = __shfl(aj, 2, 64), a3 = __shfl(aj, 3, 64);
      float a4 = __shfl(aj, 4, 64), a5 = __shfl(aj, 5, 64);
      float a6 = __shfl(aj, 6, 64), a7 = __shfl(aj, 7, 64);
      float s01 = __fadd_rn(a0, a1), s23 = __fadd_rn(a2, a3);
      float s45 = __fadd_rn(a4, a5), s67 = __fadd_rn(a6, a7);
      aj = __fadd_rn(__fadd_rn(s01, s23), __fadd_rn(s45, s67));
    }
    float mu = __fdiv_rn(aj, 128.0f);
    float d0 = __fsub_rn(r0, mu), d1 = __fsub_rn(r1, mu);
    sr[w][l] = __fmul_rn(d0, d0);
    sr[w][l + 64] = __fmul_rn(d1, d1);
    __syncthreads();
    float qj = 0.f;
    if (l < 8) {
      qj = sr[w][l];
      for (int i = 8; i < 128; i += 8) qj = __fadd_rn(qj, sr[w][i + l]);
    }
    {
      float a0 = __shfl(qj, 0, 64), a1 = __shfl(qj, 1, 64);
      float a2 = __shfl(qj, 2, 64), a3 = __shfl(qj, 3, 64);
      float a4 = __shfl(qj, 4, 64), a5 = __shfl(qj, 5, 64);
      float a6 = __shfl(qj, 6, 64), a7 = __shfl(qj, 7, 64);
      float s01 = __fadd_rn(a0, a1), s23 = __fadd_rn(a2, a3);
      float s45 = __fadd_rn(a4, a5), s67 = __fadd_rn(a6, a7);
      qj = __fadd_rn(__fadd_rn(s01, s23), __fadd_rn(s45, s67));
    }
    float var = __fdiv_rn(qj, 128.0f);
    float inv = __fdiv_rn(1.0f, sqrtf(__fadd_rn(var, 1e-5f)));
    float y0 = __fadd_rn(__fmul_rn(__fmul_rn(d0, inv), lga), lba);
    float y1 = __fadd_rn(__fmul_rn(__fmul_rn(d1, inv), lgb), lbb);
    sa[w][l] = fmaxf(y0, 0.f);
    sa[w][l + 64] = fmaxf(y1, 0.f);
    __syncthreads();

    if (l < 4) {
      float acc = 0.f;
      for (int k = 0; k < 128; ++k) acc = __fmaf_rn(sa[w][k], rtw2[k * 4 + l], acc);
      float lrn = __fadd_rn(acc, rtb2[l]);
      float dd = __fsub_rn(nl, centers[l]);
      float pr = -__fmul_rn(dd, dd);
      sb[w][4 + l] = __fadd_rn(__fmul_rn(0.65f, lrn), __fmul_rn(0.35f, pr));
    }
    __syncthreads();

    if (l == 0) {
      float lg[4] = {sb[w][4], sb[w][5], sb[w][6], sb[w][7]};
      float mx = fmaxf(fmaxf(lg[0], lg[1]), fmaxf(lg[2], lg[3]));
      float e[4];
#pragma unroll
      for (int c = 0; c < 4; ++c)
        e[c] = (float)exp((double)__fsub_rn(lg[c], mx));
      float S = __fadd_rn(__fadd_rn(__fadd_rn(e[0], e[1]), e[2]), e[3]);
      float p[4];
#pragma unroll
      for (int c = 0; c < 4; ++c) p[c] = __fdiv_rn(e[c], S);
      int i1 = 0;
#pragma unroll
      for (int c = 1; c < 4; ++c) if (p[c] > p[i1]) i1 = c;
      int i2 = -1;
#pragma unroll
      for (int c = 0; c < 4; ++c) {
        if (c == i1) continue;
        if (i2 < 0 || p[c] > p[i2]) i2 = c;
      }
      float den = __fadd_rn(__fadd_rn(p[i1], p[i2]), 1e-8f);
      float swv[4] = {0.f, 0.f, 0.f, 0.f};
      swv[i1] = __fdiv_rn(p[i1], den);
      swv[i2] = __fdiv_rn(p[i2], den);
      *reinterpret_cast<float4*>(&sw[node * 4]) =
          make_float4(swv[0], swv[1], swv[2], swv[3]);
    }
  }
}

// ---------------- head stage 1 (pair-batched): PQ[n][e*16 + {0..5, 8..13}] ---------
__global__ void k_headPQ_b(const bf16_t* __restrict__ X2p,
                           const float* __restrict__ w_relo, const float* __restrict__ w_rooto,
                           float* __restrict__ PQ, int pe) {
  int slot = blockIdx.y, e = pe + slot;
  const bf16_t* X2 = X2p + (size_t)slot * M_PAD * 256;
  const float* wro = w_relo + (size_t)e * 256 * OUTD;
  const float* wto = w_rooto + (size_t)e * 256 * OUTD;
  int tid = threadIdx.x;
  int r = blockIdx.x * 4 + (tid >> 6);    // grid.x = N/4 exact
  int lane = tid & 63;
  int k0 = lane * 4;
  float wr_[24], wt_[24];
#pragma unroll
  for (int q = 0; q < 6; ++q) {
    float4 a = *reinterpret_cast<const float4*>(&wro[k0 * 6 + q * 4]);
    wr_[q * 4 + 0] = a.x; wr_[q * 4 + 1] = a.y; wr_[q * 4 + 2] = a.z; wr_[q * 4 + 3] = a.w;
    float4 b = *reinterpret_cast<const float4*>(&wto[k0 * 6 + q * 4]);
    wt_[q * 4 + 0] = b.x; wt_[q * 4 + 1] = b.y; wt_[q * 4 + 2] = b.z; wt_[q * 4 + 3] = b.w;
  }
  ushort4 xv4 = *reinterpret_cast<const ushort4*>(&X2[(size_t)r * 256 + k0]);
  float xv[4] = {bf2f(xv4.x), bf2f(xv4.y), bf2f(xv4.z), bf2f(xv4.w)};
  float p[12] = {0.f, 0.f, 0.f, 0.f, 0.f, 0.f, 0.f, 0.f, 0.f, 0.f, 0.f, 0.f};
#pragma unroll
  for (int jj = 0; jj < 4; ++jj)
#pragma unroll
    for (int c = 0; c < 6; ++c) {
      p[c]     += xv[jj] * wr_[jj * 6 + c];
      p[6 + c] += xv[jj] * wt_[jj * 6 + c];
    }
#pragma unroll
  for (int off = 32; off > 0; off >>= 1)
#pragma unroll
    for (int c = 0; c < 12; ++c) p[c] += __shfl_down(p[c], off, 64);
  if (lane == 0) {
#pragma unroll
    for (int c = 0; c < 6; ++c) {
      PQ[(size_t)r * 64 + e * 16 + c] = p[c];
      PQ[(size_t)r * 64 + e * 16 + 8 + c] = p[6 + c];
    }
  }
}

// ---------------- head stage 2 (all experts, single kernel) -------------------------
__global__ void k_headfin_all(const int* __restrict__ row_start,
                              const int* __restrict__ csr_src,
                              const float* __restrict__ PQ, const float* __restrict__ b_relo,
                              const float* __restrict__ sw, float* __restrict__ out) {
  int t = blockIdx.x * 256 + threadIdx.x;
  int n = t >> 3, c = t & 7;
  if (n >= N_NODES || c >= 6) return;
  int j0 = row_start[n], j1 = row_start[n + 1];
  float av0 = 0.f, av1 = 0.f, av2 = 0.f, av3 = 0.f;
  for (int j = j0; j < j1; ++j) {
    size_t base = (size_t)csr_src[j] * 64 + c;
    av0 += PQ[base];
    av1 += PQ[base + 16];
    av2 += PQ[base + 32];
    av3 += PQ[base + 48];
  }
  float4 s4 = *reinterpret_cast<const float4*>(&sw[n * 4]);
  size_t nb = (size_t)n * 64 + c;
  float v = s4.x * (av0 + b_relo[0 * 6 + c] + PQ[nb + 8]);
  v += s4.y * (av1 + b_relo[1 * 6 + c] + PQ[nb + 16 + 8]);
  v += s4.z * (av2 + b_relo[2 * 6 + c] + PQ[nb + 32 + 8]);
  v += s4.w * (av3 + b_relo[3 * 6 + c] + PQ[nb + 48 + 8]);
  out[n * 6 + c] = v;
}

// ---------------- launch ----------------
extern "C" void kernel_launch(void* const* d_in, const int* in_sizes, int n_in,
                              void* d_out, int out_size, void* d_ws, size_t ws_size,
                              hipStream_t stream) {
  const float* x        = (const float*)d_in[0];
  const int*   edge     = (const int*)d_in[1];
  const int*   batch    = (const int*)d_in[2];
  const float* enc_w1   = (const float*)d_in[4];
  const float* enc_b1   = (const float*)d_in[5];
  const float* enc_w2   = (const float*)d_in[6];
  const float* enc_b2   = (const float*)d_in[7];
  const float* rt_w1    = (const float*)d_in[8];
  const float* rt_b1    = (const float*)d_in[9];
  const float* ln_g     = (const float*)d_in[10];
  const float* ln_b     = (const float*)d_in[11];
  const float* rt_w2    = (const float*)d_in[12];
  const float* rt_b2    = (const float*)d_in[13];
  const float* centers  = (const float*)d_in[14];
  const float* w_rel    = (const float*)d_in[15];
  const float* b_rel    = (const float*)d_in[16];
  const float* w_root   = (const float*)d_in[17];
  const float* w_relo   = (const float*)d_in[18];
  const float* b_relo   = (const float*)d_in[19];
  const float* w_rooto  = (const float*)d_in[20];
  float* out = (float*)d_out;

  char* wsp = (char*)d_ws;
  auto alloc = [&](size_t bytes) -> char* {
    char* p = wsp;
    wsp += (bytes + 255) & ~(size_t)255;
    return p;
  };
  const size_t actF32 = (size_t)M_PAD * 256 * sizeof(float);    // 51.25 MB
  const size_t actB16 = (size_t)M_PAD * 256 * sizeof(bf16_t);   // 25.63 MB
  char*   hx  = alloc(actF32);    // h; doubles as X1/X2 pair after router
  float*  h   = (float*)hx;
  bf16_t* X1p = (bf16_t*)hx;
  char*   tx  = alloc(actF32);    // t; doubles as A1 pair after encoder GEMM
  float*  t   = (float*)tx;
  bf16_t* A1p = (bf16_t*)tx;
  bf16_t* hb  = (bf16_t*)alloc(actB16);
  bf16_t* AGG = (bf16_t*)alloc(actB16);
  bf16_t* WT  = (bf16_t*)alloc((size_t)16 * 65536 * sizeof(bf16_t));
  float* PQ   = (float*)alloc((size_t)N_NODES * 64 * sizeof(float));   // 12.8 MB
  float* swp  = (float*)alloc((size_t)N_NODES * 4 * sizeof(float));
  int*   n_cnt = (int*)alloc(NG * sizeof(int));
  int*   e_cnt = (int*)alloc(NG * sizeof(int));
  float* gfbuf = (float*)alloc(NG * 2 * sizeof(float));
  float* lnn   = (float*)alloc(NG * sizeof(float));
  int* deg       = (int*)alloc((size_t)N_NODES * sizeof(int));
  int* row_start = (int*)alloc((size_t)(N_NODES + 1) * sizeof(int));
  int* cursor    = (int*)alloc((size_t)N_NODES * sizeof(int));
  int* csr_src   = (int*)alloc((size_t)NUM_EDGES * sizeof(int));

  // graph stats + CSR build + weight prep
  k_zero<<<(N_NODES + 255) / 256, 256, 0, stream>>>(deg, n_cnt, e_cnt);
  k_count_nodes<<<(N_NODES + 255) / 256, 256, 0, stream>>>(batch, n_cnt);
  k_count_edges<<<(NUM_EDGES + 255) / 256, 256, 0, stream>>>(edge, batch, e_cnt, deg);
  k_graph_stats<<<1, 64, 0, stream>>>(n_cnt, e_cnt, gfbuf, lnn);
  k_scan<<<1, 1024, 0, stream>>>(deg, row_start, cursor);
  k_fill<<<(NUM_EDGES + 255) / 256, 256, 0, stream>>>(edge, cursor, csr_src);
  dim3 wgrid(16, 4);
  k_wprep<<<wgrid, 256, 0, stream>>>(w_rel, w_root, WT);

  // encoder (frozen math; epilogue also writes hb)
  k_enc1<<<(N_NODES + 15) / 16, 256, 0, stream>>>(x, enc_w1, enc_b1, t);
  dim3 egrid(M_PAD / 128, 2);
  k_gemm_enc<<<egrid, 256, 0, stream>>>(t, enc_w2, enc_b2, h, hb, N_NODES);

  // router (LDS-free main loop; bit-identical arithmetic)
  k_router_np<<<N_NODES / 16, 256, 0, stream>>>(
      h, batch, gfbuf, lnn, rt_w1, rt_b1, ln_g, ln_b, rt_w2, rt_b2, centers, swp);

  // loop-invariant agg_h (after router: X1p will overwrite h)
  k_gather<<<N_NODES / 8, 256, 0, stream>>>(row_start, csr_src, hb, AGG);

  // experts, pair-batched (gridDim.y = 2)
  dim3 ggrid(M_PAD / 128, 2);
  dim3 grid_gather(N_NODES / 8, 2);
  dim3 grid_pq(N_NODES / 4, 2);
  for (int pe = 0; pe < NEXP; pe += 2) {
    k_gemm1_b<<<ggrid, 256, 0, stream>>>(AGG, hb, WT, b_rel, X1p, pe);
    k_gather_b<<<grid_gather, 256, 0, stream>>>(row_start, csr_src, X1p, A1p);
    k_gemm2_b<<<ggrid, 256, 0, stream>>>(A1p, X1p, WT, b_rel, pe);
    k_headPQ_b<<<grid_pq, 256, 0, stream>>>(X1p, w_relo, w_rooto, PQ, pe);
  }
  k_headfin_all<<<(N_NODES * 8 + 255) / 256, 256, 0, stream>>>(
      row_start, csr_src, PQ, b_relo, swp, out);
}

// Round 18
// 1311.755 us; speedup vs baseline: 1.1348x; 1.0593x over previous
//
#include <hip/hip_runtime.h>
#include <math.h>

#define N_NODES 50000
#define M_PAD 50048            // 391 * 128
#define NUM_EDGES 800000
#define NG 8
#define HID 256
#define RHD 128
#define NEXP 4
#define OUTD 6
#define NPW 8                  // router nodes per wave
#define SCAN_BLK 196           // ceil(50000/256)

typedef unsigned short bf16_t;
using f32x4  = __attribute__((ext_vector_type(4))) float;
using bf16x8 = __attribute__((ext_vector_type(8))) short;

__device__ __forceinline__ float bf2f(unsigned short u) {
  union { unsigned int i; float f; } v; v.i = ((unsigned int)u) << 16; return v.f;
}
__device__ __forceinline__ unsigned short f2bf(float f) {
  union { float f; unsigned int i; } v; v.f = f;
  unsigned int x = v.i;
  unsigned int r = x + 0x7fffu + ((x >> 16) & 1u);  // RNE
  return (unsigned short)(r >> 16);
}
__device__ __forceinline__ float readlane_f(float v, int lane) {
  return __int_as_float(__builtin_amdgcn_readlane(__float_as_int(v), lane));
}

// ---------------- zero init ----------------
__global__ void k_zero(int* __restrict__ deg, int* __restrict__ n_cnt,
                       int* __restrict__ e_cnt) {
  int i = blockIdx.x * blockDim.x + threadIdx.x;
  if (i < N_NODES) deg[i] = 0;
  if (i < NG) { n_cnt[i] = 0; e_cnt[i] = 0; }
}

// ---------------- fused node+edge counts ----------------
__global__ void k_count(const int* __restrict__ batch, const int* __restrict__ edge,
                        int* __restrict__ n_cnt, int* __restrict__ e_cnt,
                        int* __restrict__ deg) {
  __shared__ int histn[NG], histe[NG];
  int t = threadIdx.x;
  if (t < NG) { histn[t] = 0; histe[t] = 0; }
  __syncthreads();
  int i = blockIdx.x * blockDim.x + t;
  if (i < N_NODES) atomicAdd(&histn[batch[i]], 1);
  if (i < NUM_EDGES) {
    int s = edge[i];
    int d = edge[NUM_EDGES + i];
    atomicAdd(&histe[batch[s]], 1);
    atomicAdd(&deg[d], 1);
  }
  __syncthreads();
  if (t < NG) {
    if (histn[t]) atomicAdd(&n_cnt[t], histn[t]);
    if (histe[t]) atomicAdd(&e_cnt[t], histe[t]);
  }
}

// numpy-faithful f32 stats (frozen: razor-sensitive)
__device__ __forceinline__ float tree8(const float* v) {
  float s01 = __fadd_rn(v[0], v[1]);
  float s23 = __fadd_rn(v[2], v[3]);
  float s45 = __fadd_rn(v[4], v[5]);
  float s67 = __fadd_rn(v[6], v[7]);
  return __fadd_rn(__fadd_rn(s01, s23), __fadd_rn(s45, s67));
}

__global__ void k_graph_stats(const int* __restrict__ n_cnt, const int* __restrict__ e_cnt,
                              float* __restrict__ gf, float* __restrict__ lnn) {
  if (threadIdx.x != 0 || blockIdx.x != 0) return;
  float logn[NG], loge[NG];
  for (int g = 0; g < NG; ++g) {
    float nf = fmaxf((float)n_cnt[g], 1.0f);
    logn[g] = (float)log((double)nf);
    float ef = fmaxf((float)e_cnt[g], 0.0f);
    loge[g] = (float)log1p((double)ef);
  }
  float m0 = __fdiv_rn(tree8(logn), 8.0f);
  float m1 = __fdiv_rn(tree8(loge), 8.0f);
  float sq0[NG], sq1[NG];
  float mn = 3.0e38f, mx = -3.0e38f;
  for (int g = 0; g < NG; ++g) {
    float d0 = __fsub_rn(logn[g], m0);
    float d1 = __fsub_rn(loge[g], m1);
    sq0[g] = __fmul_rn(d0, d0);
    sq1[g] = __fmul_rn(d1, d1);
    mn = fminf(mn, logn[g]); mx = fmaxf(mx, logn[g]);
  }
  float s0 = __fadd_rn(sqrtf(__fdiv_rn(tree8(sq0), 8.0f)), 1e-6f);
  float s1 = __fadd_rn(sqrtf(__fdiv_rn(tree8(sq1), 8.0f)), 1e-6f);
  float denom = __fadd_rn(__fsub_rn(mx, mn), 1e-6f);
  for (int g = 0; g < NG; ++g) {
    gf[g * 2 + 0] = __fdiv_rn(__fsub_rn(logn[g], m0), s0);
    gf[g * 2 + 1] = __fdiv_rn(__fsub_rn(loge[g], m1), s1);
    lnn[g] = __fdiv_rn(__fsub_rn(logn[g], mn), denom);
  }
}

// ---------------- CSR build: two-level parallel scan ----------------
__global__ void k_scan_a(const int* __restrict__ deg, int* __restrict__ excl,
                         int* __restrict__ bsum) {
  __shared__ int temp[256];
  int b = blockIdx.x, t = threadIdx.x;
  int i = b * 256 + t;
  int v = (i < N_NODES) ? deg[i] : 0;
  temp[t] = v;
  __syncthreads();
  for (int off = 1; off < 256; off <<= 1) {
    int x = (t >= off) ? temp[t - off] : 0;
    __syncthreads();
    temp[t] += x;
    __syncthreads();
  }
  if (i < N_NODES) excl[i] = temp[t] - v;
  if (t == 255) bsum[b] = temp[255];
}

__global__ void k_scan_b(const int* __restrict__ bsum, int* __restrict__ boff,
                         int* __restrict__ row_start) {
  __shared__ int temp[256];
  int t = threadIdx.x;
  int v = (t < SCAN_BLK) ? bsum[t] : 0;
  temp[t] = v;
  __syncthreads();
  for (int off = 1; off < 256; off <<= 1) {
    int x = (t >= off) ? temp[t - off] : 0;
    __syncthreads();
    temp[t] += x;
    __syncthreads();
  }
  if (t < SCAN_BLK) boff[t] = temp[t] - v;
  if (t == SCAN_BLK - 1) row_start[N_NODES] = temp[t];
}

__global__ void k_scan_c(const int* __restrict__ excl, const int* __restrict__ boff,
                         int* __restrict__ row_start, int* __restrict__ cursor) {
  int i = blockIdx.x * 256 + threadIdx.x;
  if (i < N_NODES) {
    int e = excl[i] + boff[blockIdx.x];
    row_start[i] = e;
    cursor[i] = e;
  }
}

__global__ void k_fill(const int* __restrict__ edge, int* __restrict__ cursor,
                       int* __restrict__ csr_src) {
  int i = blockIdx.x * blockDim.x + threadIdx.x;
  if (i < NUM_EDGES) {
    int d = edge[NUM_EDGES + i];
    int p = atomicAdd(&cursor[d], 1);
    csr_src[p] = edge[i];
  }
}

// ---------------- encoder layer 1 (frozen) -----------------------------------------
__global__ void k_enc1(const float* __restrict__ x, const float* __restrict__ w1,
                       const float* __restrict__ b1, float* __restrict__ t) {
  __shared__ float W[6 * 256];
  __shared__ float xs[16][6];
  int tid = threadIdx.x;
  for (int i = tid; i < 6 * 256; i += 256) W[i] = w1[i];
  int base = blockIdx.x * 16;
  if (tid < 96) {
    int n = tid / 6, k = tid % 6;
    int node = base + n;
    xs[n][k] = (node < N_NODES) ? x[node * 16 + 4 + k] : 0.f;
  }
  __syncthreads();
  float b = b1[tid];
  for (int n = 0; n < 16; ++n) {
    int node = base + n;
    if (node >= N_NODES) break;
    float acc = 0.f;
#pragma unroll
    for (int k = 0; k < 6; ++k) acc = __fmaf_rn(xs[n][k], W[k * 256 + tid], acc);
    t[node * 256 + tid] = fmaxf(__fadd_rn(acc, b), 0.f);
  }
}

// ---------------- fp32 SIMT GEMM (frozen math; epilogue also emits bf16 copy) -------
__global__ __launch_bounds__(256, 2) void k_gemm_enc(
    const float* __restrict__ A, const float* __restrict__ W0,
    const float* __restrict__ bias, float* __restrict__ C,
    bf16_t* __restrict__ Cb, int M) {
  __shared__ float As[16][132];
  __shared__ float Ws[16][128];
  const int tid = threadIdx.x;
  const int tx = tid & 15;
  const int ty = tid >> 4;
  const int rowBase = blockIdx.x * 128;
  const int colBase = blockIdx.y * 128;

  float acc[2][2][4][4];
#pragma unroll
  for (int a = 0; a < 2; ++a)
#pragma unroll
    for (int b = 0; b < 2; ++b)
#pragma unroll
      for (int i = 0; i < 4; ++i)
#pragma unroll
        for (int j = 0; j < 4; ++j) acc[a][b][i][j] = 0.f;

  for (int kt = 0; kt < 16; ++kt) {
    const int kb = kt * 16;
#pragma unroll
    for (int l = 0; l < 2; ++l) {
      int idx = tid + l * 256;
      int m = idx >> 2;
      int kq = (idx & 3) * 4;
      int arow = rowBase + m;
      float4 av = make_float4(0.f, 0.f, 0.f, 0.f);
      if (arow < M) av = *reinterpret_cast<const float4*>(&A[arow * 256 + kb + kq]);
      As[kq + 0][m] = av.x; As[kq + 1][m] = av.y;
      As[kq + 2][m] = av.z; As[kq + 3][m] = av.w;
    }
#pragma unroll
    for (int l = 0; l < 2; ++l) {
      int idx = tid + l * 256;
      int k = idx >> 5;
      int nq = (idx & 31) * 4;
      float4 wv = *reinterpret_cast<const float4*>(&W0[(kb + k) * 256 + colBase + nq]);
      *reinterpret_cast<float4*>(&Ws[k][nq]) = wv;
    }
    __syncthreads();
#pragma unroll
    for (int k = 0; k < 16; ++k) {
      float4 a0 = *reinterpret_cast<const float4*>(&As[k][ty * 4]);
      float4 a1 = *reinterpret_cast<const float4*>(&As[k][64 + ty * 4]);
      float4 w0 = *reinterpret_cast<const float4*>(&Ws[k][tx * 4]);
      float4 w1 = *reinterpret_cast<const float4*>(&Ws[k][64 + tx * 4]);
      float ar[2][4] = {{a0.x, a0.y, a0.z, a0.w}, {a1.x, a1.y, a1.z, a1.w}};
      float wr[2][4] = {{w0.x, w0.y, w0.z, w0.w}, {w1.x, w1.y, w1.z, w1.w}};
#pragma unroll
      for (int ri = 0; ri < 2; ++ri)
#pragma unroll
        for (int i = 0; i < 4; ++i)
#pragma unroll
          for (int ci = 0; ci < 2; ++ci)
#pragma unroll
            for (int j = 0; j < 4; ++j)
              acc[ri][ci][i][j] = __fmaf_rn(ar[ri][i], wr[ci][j], acc[ri][ci][i][j]);
    }
    __syncthreads();
  }
  float4 bv0 = *reinterpret_cast<const float4*>(&bias[colBase + tx * 4]);
  float4 bv1 = *reinterpret_cast<const float4*>(&bias[colBase + 64 + tx * 4]);
  float bb[2][4] = {{bv0.x, bv0.y, bv0.z, bv0.w}, {bv1.x, bv1.y, bv1.z, bv1.w}};
#pragma unroll
  for (int ri = 0; ri < 2; ++ri) {
#pragma unroll
    for (int i = 0; i < 4; ++i) {
      int row = rowBase + ri * 64 + ty * 4 + i;
      if (row < M) {
#pragma unroll
        for (int ci = 0; ci < 2; ++ci) {
          float o[4];
#pragma unroll
          for (int j = 0; j < 4; ++j)
            o[j] = __fadd_rn(acc[ri][ci][i][j], bb[ci][j]);
          *reinterpret_cast<float4*>(&C[row * 256 + colBase + ci * 64 + tx * 4]) =
              make_float4(o[0], o[1], o[2], o[3]);
          ushort4 ob = make_ushort4(f2bf(o[0]), f2bf(o[1]), f2bf(o[2]), f2bf(o[3]));
          *reinterpret_cast<ushort4*>(&Cb[(size_t)row * 256 + colBase + ci * 64 + tx * 4]) = ob;
        }
      }
    }
  }
}

// ---------------- weight prep: transpose f32 [k][n] -> bf16 [n][k] ------------------
__global__ void k_wprep(const float* __restrict__ w_rel, const float* __restrict__ w_root,
                        bf16_t* __restrict__ WT) {
  __shared__ bf16_t tile[64][258];
  int m = blockIdx.x;
  int k0 = blockIdx.y * 64;
  const float* src = (m < 8) ? (w_rel + (size_t)m * 65536)
                             : (w_root + (size_t)(m - 8) * 65536);
  bf16_t* dst = WT + (size_t)m * 65536;
  int tid = threadIdx.x;
  for (int r = 0; r < 64; ++r)
    tile[r][tid] = f2bf(src[(k0 + r) * 256 + tid]);
  __syncthreads();
  for (int c = 0; c < 64; c += 8) {
    ushort4 lo, hi;
    lo.x = tile[c + 0][tid]; lo.y = tile[c + 1][tid];
    lo.z = tile[c + 2][tid]; lo.w = tile[c + 3][tid];
    hi.x = tile[c + 4][tid]; hi.y = tile[c + 5][tid];
    hi.z = tile[c + 6][tid]; hi.w = tile[c + 7][tid];
    *reinterpret_cast<ushort4*>(&dst[tid * 256 + k0 + c]) = lo;
    *reinterpret_cast<ushort4*>(&dst[tid * 256 + k0 + c + 4]) = hi;
  }
}

// ---------------- LDS-free MFMA bf16 GEMM core (BM=128, BN=256), bf16 out -----------
__device__ __forceinline__ void gemm_core(
    const bf16_t* __restrict__ A, const bf16_t* __restrict__ W0t,
    const bf16_t* __restrict__ B, const bf16_t* __restrict__ W1t,
    const float* __restrict__ bias, bf16_t* __restrict__ C, int rowBase) {
  const int tid = threadIdx.x;
  const int lane = tid & 63;
  const int wave = tid >> 6;
  const int lm = lane & 15;
  const int quad = lane >> 4;
  const int wm = (wave >> 1) * 64;
  const int wn = (wave & 1) * 128;

  f32x4 acc[4][8];
#pragma unroll
  for (int i = 0; i < 4; ++i)
#pragma unroll
    for (int j = 0; j < 8; ++j) acc[i][j] = (f32x4){0.f, 0.f, 0.f, 0.f};

#pragma unroll
  for (int phase = 0; phase < 2; ++phase) {
    const bf16_t* __restrict__ Ain = phase ? B : A;
    const bf16_t* __restrict__ Wt  = phase ? W1t : W0t;
    const bf16_t* ap[4];
    const bf16_t* bp[8];
#pragma unroll
    for (int i = 0; i < 4; ++i)
      ap[i] = Ain + (size_t)(rowBase + wm + i * 16 + lm) * 256 + quad * 8;
#pragma unroll
    for (int j = 0; j < 8; ++j)
      bp[j] = Wt + (size_t)(wn + j * 16 + lm) * 256 + quad * 8;
    for (int kt = 0; kt < 8; ++kt) {
      bf16x8 af[4], bfr[8];
#pragma unroll
      for (int i = 0; i < 4; ++i)
        af[i] = *reinterpret_cast<const bf16x8*>(ap[i] + kt * 32);
#pragma unroll
      for (int j = 0; j < 8; ++j)
        bfr[j] = *reinterpret_cast<const bf16x8*>(bp[j] + kt * 32);
#pragma unroll
      for (int i = 0; i < 4; ++i)
#pragma unroll
        for (int j = 0; j < 8; ++j)
          acc[i][j] = __builtin_amdgcn_mfma_f32_16x16x32_bf16(af[i], bfr[j], acc[i][j], 0, 0, 0);
    }
  }
  float bj[8];
#pragma unroll
  for (int j = 0; j < 8; ++j) bj[j] = bias[wn + j * 16 + lm];
#pragma unroll
  for (int i = 0; i < 4; ++i) {
#pragma unroll
    for (int j = 0; j < 8; ++j) {
      int col = wn + j * 16 + lm;
#pragma unroll
      for (int r = 0; r < 4; ++r) {
        int row = rowBase + wm + i * 16 + quad * 4 + r;
        C[(size_t)row * 256 + col] = f2bf(fmaxf(acc[i][j][r] + bj[j], 0.f));
      }
    }
  }
}

// pair-batched GEMM1: X1[slot] = relu(AGG@wr0_e + hb@wo0_e + br0_e), e = pe + slot
__global__ __launch_bounds__(256) void k_gemm1_b(
    const bf16_t* __restrict__ AGG, const bf16_t* __restrict__ hb,
    const bf16_t* __restrict__ WT, const float* __restrict__ b_rel,
    bf16_t* __restrict__ X1p, int pe) {
  int slot = blockIdx.y, e = pe + slot;
  gemm_core(AGG, WT + (size_t)(e * 2) * 65536,
            hb, WT + (size_t)(8 + e * 2) * 65536,
            b_rel + (size_t)(e * 2) * 256,
            X1p + (size_t)slot * M_PAD * 256, blockIdx.x * 128);
}

// pair-batched GEMM2 (in-place): X2[slot] = relu(A1[slot]@wr1_e + X1[slot]@wo1_e + br1_e)
__global__ __launch_bounds__(256) void k_gemm2_b(
    const bf16_t* __restrict__ A1p, bf16_t* __restrict__ X1p,
    const bf16_t* __restrict__ WT, const float* __restrict__ b_rel, int pe) {
  int slot = blockIdx.y, e = pe + slot;
  bf16_t* Xs = X1p + (size_t)slot * M_PAD * 256;
  gemm_core(A1p + (size_t)slot * M_PAD * 256, WT + (size_t)(e * 2 + 1) * 65536,
            Xs, WT + (size_t)(8 + e * 2 + 1) * 65536,
            b_rel + (size_t)(e * 2 + 1) * 256, Xs, blockIdx.x * 128);
}

// ---------------- CSR gather, bf16 in/out (f32 accumulate, unroll-2) ----------------
__device__ __forceinline__ void gather_core(
    const int* __restrict__ row_start, const int* __restrict__ csr_src,
    const bf16_t* __restrict__ X, bf16_t* __restrict__ Cout) {
  int tid = threadIdx.x;
  int r = blockIdx.x * 8 + (tid >> 5);
  int f = (tid & 31) * 8;
  int j0 = row_start[r], j1 = row_start[r + 1];
  float a[8] = {0.f, 0.f, 0.f, 0.f, 0.f, 0.f, 0.f, 0.f};
  int j = j0;
  for (; j + 1 < j1; j += 2) {
    int s0 = csr_src[j];
    int s1 = csr_src[j + 1];
    bf16x8 v0 = *reinterpret_cast<const bf16x8*>(&X[(size_t)s0 * 256 + f]);
    bf16x8 v1 = *reinterpret_cast<const bf16x8*>(&X[(size_t)s1 * 256 + f]);
#pragma unroll
    for (int t = 0; t < 8; ++t) a[t] += bf2f((unsigned short)v0[t]);
#pragma unroll
    for (int t = 0; t < 8; ++t) a[t] += bf2f((unsigned short)v1[t]);
  }
  if (j < j1) {
    int s = csr_src[j];
    bf16x8 v = *reinterpret_cast<const bf16x8*>(&X[(size_t)s * 256 + f]);
#pragma unroll
    for (int t = 0; t < 8; ++t) a[t] += bf2f((unsigned short)v[t]);
  }
  ushort4 lo = make_ushort4(f2bf(a[0]), f2bf(a[1]), f2bf(a[2]), f2bf(a[3]));
  ushort4 hi = make_ushort4(f2bf(a[4]), f2bf(a[5]), f2bf(a[6]), f2bf(a[7]));
  *reinterpret_cast<ushort4*>(&Cout[(size_t)r * 256 + f]) = lo;
  *reinterpret_cast<ushort4*>(&Cout[(size_t)r * 256 + f + 4]) = hi;
}

__global__ void k_gather(const int* __restrict__ row_start, const int* __restrict__ csr_src,
                         const bf16_t* __restrict__ X, bf16_t* __restrict__ Cout) {
  gather_core(row_start, csr_src, X, Cout);
}

__global__ void k_gather_b(const int* __restrict__ row_start, const int* __restrict__ csr_src,
                           const bf16_t* __restrict__ X1p, bf16_t* __restrict__ A1p) {
  size_t off = (size_t)blockIdx.y * M_PAD * 256;
  gather_core(row_start, csr_src, X1p + off, A1p + off);
}

// ---------------- numpy-faithful f32 router: LDS-free, 8 nodes/wave -----------------
// Per-(node,col) arithmetic BIT-IDENTICAL to r7..r17 (ascending k chain, readlane
// h broadcast, global weight loads, gf-then-bias, pairwise-8 LN, f64 exp). Only the
// per-wave node batch grew 4 -> 8, halving L2 weight re-reads. Guarded for N pad.
__global__ __launch_bounds__(256) void k_router_np(
    const float* __restrict__ h, const int* __restrict__ batch,
    const float* __restrict__ gf, const float* __restrict__ lnn,
    const float* __restrict__ rtw1, const float* __restrict__ rtb1,
    const float* __restrict__ lng, const float* __restrict__ lnb,
    const float* __restrict__ rtw2, const float* __restrict__ rtb2,
    const float* __restrict__ centers, float* __restrict__ sw) {
  __shared__ float sr[4][128];
  __shared__ float sa[4][128];
  __shared__ float sb[4][8];
  const int tid = threadIdx.x;
  const int w = tid >> 6;
  const int l = tid & 63;
  const int nbase = blockIdx.x * (4 * NPW) + w * NPW;   // grid = 1563

  float hreg[NPW][4];
#pragma unroll
  for (int nn = 0; nn < NPW; ++nn) {
    int node = nbase + nn;
#pragma unroll
    for (int j = 0; j < 4; ++j)
      hreg[nn][j] = (node < N_NODES) ? h[(size_t)node * 256 + j * 64 + l] : 0.f;
  }

  float acc0[NPW], acc1[NPW];
#pragma unroll
  for (int nn = 0; nn < NPW; ++nn) { acc0[nn] = 0.f; acc1[nn] = 0.f; }
#pragma unroll
  for (int j = 0; j < 4; ++j) {
#pragma unroll 8
    for (int k2 = 0; k2 < 64; ++k2) {
      int k = j * 64 + k2;
      float w0 = rtw1[k * RHD + l];
      float w1 = rtw1[k * RHD + l + 64];
#pragma unroll
      for (int nn = 0; nn < NPW; ++nn) {
        float hv = readlane_f(hreg[nn][j], k2);
        acc0[nn] = __fmaf_rn(hv, w0, acc0[nn]);
        acc1[nn] = __fmaf_rn(hv, w1, acc1[nn]);
      }
    }
  }

  float g0a = rtw1[256 * RHD + l],      g1a = rtw1[257 * RHD + l];
  float g0b = rtw1[256 * RHD + l + 64], g1b = rtw1[257 * RHD + l + 64];
  float b0 = rtb1[l], b1v = rtb1[l + 64];
  float lga = lng[l], lgb = lng[l + 64];
  float lba = lnb[l], lbb = lnb[l + 64];

  for (int nn = 0; nn < NPW; ++nn) {
    int node = nbase + nn;
    int g = (node < N_NODES) ? batch[node] : 0;
    float gf0 = gf[g * 2 + 0], gf1 = gf[g * 2 + 1], nl = lnn[g];
    float t0 = acc0[nn], t1 = acc1[nn];
    t0 = __fmaf_rn(gf0, g0a, t0);
    t0 = __fmaf_rn(gf1, g1a, t0);
    t1 = __fmaf_rn(gf0, g0b, t1);
    t1 = __fmaf_rn(gf1, g1b, t1);
    float r0 = __fadd_rn(t0, b0);
    float r1 = __fadd_rn(t1, b1v);
    __syncthreads();
    sr[w][l] = r0; sr[w][l + 64] = r1;
    __syncthreads();

    float aj = 0.f;
    if (l < 8) {
      aj = sr[w][l];
      for (int i = 8; i < 128; i += 8) aj = __fadd_rn(aj, sr[w][i + l]);
    }
    {
      float a0 = __shfl(aj, 0, 64), a1 = __shfl(aj, 1, 64);
      float a2 = __shfl(aj, 2, 64), a3 = __shfl(aj, 3, 64);
      float a4 = __shfl(aj, 4, 64), a5 = __shfl(aj, 5, 64);
      float a6 = __shfl(aj, 6, 64), a7 = __shfl(aj, 7, 64);
      float s01 = __fadd_rn(a0, a1), s23 = __fadd_rn(a2, a3);
      float s45 = __fadd_rn(a4, a5), s67 = __fadd_rn(a6, a7);
      aj = __fadd_rn(__fadd_rn(s01, s23), __fadd_rn(s45, s67));
    }
    float mu = __fdiv_rn(aj, 128.0f);
    float d0 = __fsub_rn(r0, mu), d1 = __fsub_rn(r1, mu);
    sr[w][l] = __fmul_rn(d0, d0);
    sr[w][l + 64] = __fmul_rn(d1, d1);
    __syncthreads();
    float qj = 0.f;
    if (l < 8) {
      qj = sr[w][l];
      for (int i = 8; i < 128; i += 8) qj = __fadd_rn(qj, sr[w][i + l]);
    }
    {
      float a0 = __shfl(qj, 0, 64), a1 = __shfl(qj, 1, 64);
      float a2 = __shfl(qj, 2, 64), a3 = __shfl(qj, 3, 64);
      float a4 = __shfl(qj, 4, 64), a5 = __shfl(qj, 5, 64);
      float a6 = __shfl(qj, 6, 64), a7 = __shfl(qj, 7, 64);
      float s01 = __fadd_rn(a0, a1), s23 = __fadd_rn(a2, a3);
      float s45 = __fadd_rn(a4, a5), s67 = __fadd_rn(a6, a7);
      qj = __fadd_rn(__fadd_rn(s01, s23), __fadd_rn(s45, s67));
    }
    float var = __fdiv_rn(qj, 128.0f);
    float inv = __fdiv_rn(1.0f, sqrtf(__fadd_rn(var, 1e-5f)));
    float y0 = __fadd_rn(__fmul_rn(__fmul_rn(d0, inv), lga), lba);
    float y1 = __fadd_rn(__fmul_rn(__fmul_rn(d1, inv), lgb), lbb);
    sa[w][l] = fmaxf(y0, 0.f);
    sa[w][l + 64] = fmaxf(y1, 0.f);
    __syncthreads();

    if (l < 4) {
      float acc = 0.f;
      for (int k = 0; k < 128; ++k) acc = __fmaf_rn(sa[w][k], rtw2[k * 4 + l], acc);
      float lrn = __fadd_rn(acc, rtb2[l]);
      float dd = __fsub_rn(nl, centers[l]);
      float pr = -__fmul_rn(dd, dd);
      sb[w][4 + l] = __fadd_rn(__fmul_rn(0.65f, lrn), __fmul_rn(0.35f, pr));
    }
    __syncthreads();

    if (l == 0 && node < N_NODES) {
      float lg[4] = {sb[w][4], sb[w][5], sb[w][6], sb[w][7]};
      float mx = fmaxf(fmaxf(lg[0], lg[1]), fmaxf(lg[2], lg[3]));
      float e[4];
#pragma unroll
      for (int c = 0; c < 4; ++c)
        e[c] = (float)exp((double)__fsub_rn(lg[c], mx));
      float S = __fadd_rn(__fadd_rn(__fadd_rn(e[0], e[1]), e[2]), e[3]);
      float p[4];
#pragma unroll
      for (int c = 0; c < 4; ++c) p[c] = __fdiv_rn(e[c], S);
      int i1 = 0;
#pragma unroll
      for (int c = 1; c < 4; ++c) if (p[c] > p[i1]) i1 = c;
      int i2 = -1;
#pragma unroll
      for (int c = 0; c < 4; ++c) {
        if (c == i1) continue;
        if (i2 < 0 || p[c] > p[i2]) i2 = c;
      }
      float den = __fadd_rn(__fadd_rn(p[i1], p[i2]), 1e-8f);
      float swv[4] = {0.f, 0.f, 0.f, 0.f};
      swv[i1] = __fdiv_rn(p[i1], den);
      swv[i2] = __fdiv_rn(p[i2], den);
      *reinterpret_cast<float4*>(&sw[node * 4]) =
          make_float4(swv[0], swv[1], swv[2], swv[3]);
    }
  }
}

// ---------------- head stage 1 (pair-batched): PQ[n][e*16 + {0..5, 8..13}] ---------
__global__ void k_headPQ_b(const bf16_t* __restrict__ X2p,
                           const float* __restrict__ w_relo, const float* __restrict__ w_rooto,
                           float* __restrict__ PQ, int pe) {
  int slot = blockIdx.y, e = pe + slot;
  const bf16_t* X2 = X2p + (size_t)slot * M_PAD * 256;
  const float* wro = w_relo + (size_t)e * 256 * OUTD;
  const float* wto = w_rooto + (size_t)e * 256 * OUTD;
  int tid = threadIdx.x;
  int r = blockIdx.x * 4 + (tid >> 6);    // grid.x = N/4 exact
  int lane = tid & 63;
  int k0 = lane * 4;
  float wr_[24], wt_[24];
#pragma unroll
  for (int q = 0; q < 6; ++q) {
    float4 a = *reinterpret_cast<const float4*>(&wro[k0 * 6 + q * 4]);
    wr_[q * 4 + 0] = a.x; wr_[q * 4 + 1] = a.y; wr_[q * 4 + 2] = a.z; wr_[q * 4 + 3] = a.w;
    float4 b = *reinterpret_cast<const float4*>(&wto[k0 * 6 + q * 4]);
    wt_[q * 4 + 0] = b.x; wt_[q * 4 + 1] = b.y; wt_[q * 4 + 2] = b.z; wt_[q * 4 + 3] = b.w;
  }
  ushort4 xv4 = *reinterpret_cast<const ushort4*>(&X2[(size_t)r * 256 + k0]);
  float xv[4] = {bf2f(xv4.x), bf2f(xv4.y), bf2f(xv4.z), bf2f(xv4.w)};
  float p[12] = {0.f, 0.f, 0.f, 0.f, 0.f, 0.f, 0.f, 0.f, 0.f, 0.f, 0.f, 0.f};
#pragma unroll
  for (int jj = 0; jj < 4; ++jj)
#pragma unroll
    for (int c = 0; c < 6; ++c) {
      p[c]     += xv[jj] * wr_[jj * 6 + c];
      p[6 + c] += xv[jj] * wt_[jj * 6 + c];
    }
#pragma unroll
  for (int off = 32; off > 0; off >>= 1)
#pragma unroll
    for (int c = 0; c < 12; ++c) p[c] += __shfl_down(p[c], off, 64);
  if (lane == 0) {
#pragma unroll
    for (int c = 0; c < 6; ++c) {
      PQ[(size_t)r * 64 + e * 16 + c] = p[c];
      PQ[(size_t)r * 64 + e * 16 + 8 + c] = p[6 + c];
    }
  }
}

// ---------------- head stage 2 (all experts, single kernel) -------------------------
__global__ void k_headfin_all(const int* __restrict__ row_start,
                              const int* __restrict__ csr_src,
                              const float* __restrict__ PQ, const float* __restrict__ b_relo,
                              const float* __restrict__ sw, float* __restrict__ out) {
  int t = blockIdx.x * 256 + threadIdx.x;
  int n = t >> 3, c = t & 7;
  if (n >= N_NODES || c >= 6) return;
  int j0 = row_start[n], j1 = row_start[n + 1];
  float av0 = 0.f, av1 = 0.f, av2 = 0.f, av3 = 0.f;
  for (int j = j0; j < j1; ++j) {
    size_t base = (size_t)csr_src[j] * 64 + c;
    av0 += PQ[base];
    av1 += PQ[base + 16];
    av2 += PQ[base + 32];
    av3 += PQ[base + 48];
  }
  float4 s4 = *reinterpret_cast<const float4*>(&sw[n * 4]);
  size_t nb = (size_t)n * 64 + c;
  float v = s4.x * (av0 + b_relo[0 * 6 + c] + PQ[nb + 8]);
  v += s4.y * (av1 + b_relo[1 * 6 + c] + PQ[nb + 16 + 8]);
  v += s4.z * (av2 + b_relo[2 * 6 + c] + PQ[nb + 32 + 8]);
  v += s4.w * (av3 + b_relo[3 * 6 + c] + PQ[nb + 48 + 8]);
  out[n * 6 + c] = v;
}

// ---------------- launch ----------------
extern "C" void kernel_launch(void* const* d_in, const int* in_sizes, int n_in,
                              void* d_out, int out_size, void* d_ws, size_t ws_size,
                              hipStream_t stream) {
  const float* x        = (const float*)d_in[0];
  const int*   edge     = (const int*)d_in[1];
  const int*   batch    = (const int*)d_in[2];
  const float* enc_w1   = (const float*)d_in[4];
  const float* enc_b1   = (const float*)d_in[5];
  const float* enc_w2   = (const float*)d_in[6];
  const float* enc_b2   = (const float*)d_in[7];
  const float* rt_w1    = (const float*)d_in[8];
  const float* rt_b1    = (const float*)d_in[9];
  const float* ln_g     = (const float*)d_in[10];
  const float* ln_b     = (const float*)d_in[11];
  const float* rt_w2    = (const float*)d_in[12];
  const float* rt_b2    = (const float*)d_in[13];
  const float* centers  = (const float*)d_in[14];
  const float* w_rel    = (const float*)d_in[15];
  const float* b_rel    = (const float*)d_in[16];
  const float* w_root   = (const float*)d_in[17];
  const float* w_relo   = (const float*)d_in[18];
  const float* b_relo   = (const float*)d_in[19];
  const float* w_rooto  = (const float*)d_in[20];
  float* out = (float*)d_out;

  char* wsp = (char*)d_ws;
  auto alloc = [&](size_t bytes) -> char* {
    char* p = wsp;
    wsp += (bytes + 255) & ~(size_t)255;
    return p;
  };
  const size_t actF32 = (size_t)M_PAD * 256 * sizeof(float);    // 51.25 MB
  const size_t actB16 = (size_t)M_PAD * 256 * sizeof(bf16_t);   // 25.63 MB
  char*   hx  = alloc(actF32);    // h; doubles as X1/X2 pair after router
  float*  h   = (float*)hx;
  bf16_t* X1p = (bf16_t*)hx;
  char*   tx  = alloc(actF32);    // t; doubles as A1 pair after encoder GEMM
  float*  t   = (float*)tx;
  bf16_t* A1p = (bf16_t*)tx;
  bf16_t* hb  = (bf16_t*)alloc(actB16);
  bf16_t* AGG = (bf16_t*)alloc(actB16);
  bf16_t* WT  = (bf16_t*)alloc((size_t)16 * 65536 * sizeof(bf16_t));
  float* PQ   = (float*)alloc((size_t)N_NODES * 64 * sizeof(float));   // 12.8 MB
  float* swp  = (float*)alloc((size_t)N_NODES * 4 * sizeof(float));
  int*   n_cnt = (int*)alloc(NG * sizeof(int));
  int*   e_cnt = (int*)alloc(NG * sizeof(int));
  float* gfbuf = (float*)alloc(NG * 2 * sizeof(float));
  float* lnn   = (float*)alloc(NG * sizeof(float));
  int* deg       = (int*)alloc((size_t)N_NODES * sizeof(int));
  int* row_start = (int*)alloc((size_t)(N_NODES + 1) * sizeof(int));
  int* cursor    = (int*)alloc((size_t)N_NODES * sizeof(int));
  int* excl      = (int*)alloc((size_t)N_NODES * sizeof(int));
  int* bsum      = (int*)alloc(SCAN_BLK * sizeof(int));
  int* boff      = (int*)alloc(SCAN_BLK * sizeof(int));
  int* csr_src   = (int*)alloc((size_t)NUM_EDGES * sizeof(int));

  // graph stats + CSR build + weight prep
  k_zero<<<(N_NODES + 255) / 256, 256, 0, stream>>>(deg, n_cnt, e_cnt);
  k_count<<<(NUM_EDGES + 255) / 256, 256, 0, stream>>>(batch, edge, n_cnt, e_cnt, deg);
  k_graph_stats<<<1, 64, 0, stream>>>(n_cnt, e_cnt, gfbuf, lnn);
  k_scan_a<<<SCAN_BLK, 256, 0, stream>>>(deg, excl, bsum);
  k_scan_b<<<1, 256, 0, stream>>>(bsum, boff, row_start);
  k_scan_c<<<SCAN_BLK, 256, 0, stream>>>(excl, boff, row_start, cursor);
  k_fill<<<(NUM_EDGES + 255) / 256, 256, 0, stream>>>(edge, cursor, csr_src);
  dim3 wgrid(16, 4);
  k_wprep<<<wgrid, 256, 0, stream>>>(w_rel, w_root, WT);

  // encoder (frozen math; epilogue also writes hb)
  k_enc1<<<(N_NODES + 15) / 16, 256, 0, stream>>>(x, enc_w1, enc_b1, t);
  dim3 egrid(M_PAD / 128, 2);
  k_gemm_enc<<<egrid, 256, 0, stream>>>(t, enc_w2, enc_b2, h, hb, N_NODES);

  // router (8 nodes/wave; bit-identical arithmetic)
  k_router_np<<<(N_NODES + 4 * NPW - 1) / (4 * NPW), 256, 0, stream>>>(
      h, batch, gfbuf, lnn, rt_w1, rt_b1, ln_g, ln_b, rt_w2, rt_b2, centers, swp);

  // loop-invariant agg_h (after router: X1p will overwrite h)
  k_gather<<<N_NODES / 8, 256, 0, stream>>>(row_start, csr_src, hb, AGG);

  // experts, pair-batched (gridDim.y = 2)
  dim3 ggrid(M_PAD / 128, 2);
  dim3 grid_gather(N_NODES / 8, 2);
  dim3 grid_pq(N_NODES / 4, 2);
  for (int pe = 0; pe < NEXP; pe += 2) {
    k_gemm1_b<<<ggrid, 256, 0, stream>>>(AGG, hb, WT, b_rel, X1p, pe);
    k_gather_b<<<grid_gather, 256, 0, stream>>>(row_start, csr_src, X1p, A1p);
    k_gemm2_b<<<ggrid, 256, 0, stream>>>(A1p, X1p, WT, b_rel, pe);
    k_headPQ_b<<<grid_pq, 256, 0, stream>>>(X1p, w_relo, w_rooto, PQ, pe);
  }
  k_headfin_all<<<(N_NODES * 8 + 255) / 256, 256, 0, stream>>>(
      row_start, csr_src, PQ, b_relo, swp, out);
}

// Round 19
// 1297.144 us; speedup vs baseline: 1.1475x; 1.0113x over previous
//
#include <hip/hip_runtime.h>
#include <math.h>

#define N_NODES 50000
#define M_PAD 50048            // 391 * 128
#define NUM_EDGES 800000
#define NG 8
#define HID 256
#define RHD 128
#define NEXP 4
#define OUTD 6
#define NPW 4                  // router nodes per wave (r15 config: 8 regressed, r18)
#define SCAN_BLK 196           // ceil(50000/256)

typedef unsigned short bf16_t;
using f32x4  = __attribute__((ext_vector_type(4))) float;
using bf16x8 = __attribute__((ext_vector_type(8))) short;

__device__ __forceinline__ float bf2f(unsigned short u) {
  union { unsigned int i; float f; } v; v.i = ((unsigned int)u) << 16; return v.f;
}
__device__ __forceinline__ unsigned short f2bf(float f) {
  union { float f; unsigned int i; } v; v.f = f;
  unsigned int x = v.i;
  unsigned int r = x + 0x7fffu + ((x >> 16) & 1u);  // RNE
  return (unsigned short)(r >> 16);
}
__device__ __forceinline__ float readlane_f(float v, int lane) {
  return __int_as_float(__builtin_amdgcn_readlane(__float_as_int(v), lane));
}

// ---------------- zero init ----------------
__global__ void k_zero(int* __restrict__ deg, int* __restrict__ n_cnt,
                       int* __restrict__ e_cnt) {
  int i = blockIdx.x * blockDim.x + threadIdx.x;
  if (i < N_NODES) deg[i] = 0;
  if (i < NG) { n_cnt[i] = 0; e_cnt[i] = 0; }
}

// ---------------- fused node+edge counts ----------------
__global__ void k_count(const int* __restrict__ batch, const int* __restrict__ edge,
                        int* __restrict__ n_cnt, int* __restrict__ e_cnt,
                        int* __restrict__ deg) {
  __shared__ int histn[NG], histe[NG];
  int t = threadIdx.x;
  if (t < NG) { histn[t] = 0; histe[t] = 0; }
  __syncthreads();
  int i = blockIdx.x * blockDim.x + t;
  if (i < N_NODES) atomicAdd(&histn[batch[i]], 1);
  if (i < NUM_EDGES) {
    int s = edge[i];
    int d = edge[NUM_EDGES + i];
    atomicAdd(&histe[batch[s]], 1);
    atomicAdd(&deg[d], 1);
  }
  __syncthreads();
  if (t < NG) {
    if (histn[t]) atomicAdd(&n_cnt[t], histn[t]);
    if (histe[t]) atomicAdd(&e_cnt[t], histe[t]);
  }
}

// numpy-faithful f32 stats (frozen: razor-sensitive)
__device__ __forceinline__ float tree8(const float* v) {
  float s01 = __fadd_rn(v[0], v[1]);
  float s23 = __fadd_rn(v[2], v[3]);
  float s45 = __fadd_rn(v[4], v[5]);
  float s67 = __fadd_rn(v[6], v[7]);
  return __fadd_rn(__fadd_rn(s01, s23), __fadd_rn(s45, s67));
}

__global__ void k_graph_stats(const int* __restrict__ n_cnt, const int* __restrict__ e_cnt,
                              float* __restrict__ gf, float* __restrict__ lnn) {
  if (threadIdx.x != 0 || blockIdx.x != 0) return;
  float logn[NG], loge[NG];
  for (int g = 0; g < NG; ++g) {
    float nf = fmaxf((float)n_cnt[g], 1.0f);
    logn[g] = (float)log((double)nf);
    float ef = fmaxf((float)e_cnt[g], 0.0f);
    loge[g] = (float)log1p((double)ef);
  }
  float m0 = __fdiv_rn(tree8(logn), 8.0f);
  float m1 = __fdiv_rn(tree8(loge), 8.0f);
  float sq0[NG], sq1[NG];
  float mn = 3.0e38f, mx = -3.0e38f;
  for (int g = 0; g < NG; ++g) {
    float d0 = __fsub_rn(logn[g], m0);
    float d1 = __fsub_rn(loge[g], m1);
    sq0[g] = __fmul_rn(d0, d0);
    sq1[g] = __fmul_rn(d1, d1);
    mn = fminf(mn, logn[g]); mx = fmaxf(mx, logn[g]);
  }
  float s0 = __fadd_rn(sqrtf(__fdiv_rn(tree8(sq0), 8.0f)), 1e-6f);
  float s1 = __fadd_rn(sqrtf(__fdiv_rn(tree8(sq1), 8.0f)), 1e-6f);
  float denom = __fadd_rn(__fsub_rn(mx, mn), 1e-6f);
  for (int g = 0; g < NG; ++g) {
    gf[g * 2 + 0] = __fdiv_rn(__fsub_rn(logn[g], m0), s0);
    gf[g * 2 + 1] = __fdiv_rn(__fsub_rn(loge[g], m1), s1);
    lnn[g] = __fdiv_rn(__fsub_rn(logn[g], mn), denom);
  }
}

// ---------------- CSR build: two-level parallel scan ----------------
__global__ void k_scan_a(const int* __restrict__ deg, int* __restrict__ excl,
                         int* __restrict__ bsum) {
  __shared__ int temp[256];
  int b = blockIdx.x, t = threadIdx.x;
  int i = b * 256 + t;
  int v = (i < N_NODES) ? deg[i] : 0;
  temp[t] = v;
  __syncthreads();
  for (int off = 1; off < 256; off <<= 1) {
    int x = (t >= off) ? temp[t - off] : 0;
    __syncthreads();
    temp[t] += x;
    __syncthreads();
  }
  if (i < N_NODES) excl[i] = temp[t] - v;
  if (t == 255) bsum[b] = temp[255];
}

__global__ void k_scan_b(const int* __restrict__ bsum, int* __restrict__ boff,
                         int* __restrict__ row_start) {
  __shared__ int temp[256];
  int t = threadIdx.x;
  int v = (t < SCAN_BLK) ? bsum[t] : 0;
  temp[t] = v;
  __syncthreads();
  for (int off = 1; off < 256; off <<= 1) {
    int x = (t >= off) ? temp[t - off] : 0;
    __syncthreads();
    temp[t] += x;
    __syncthreads();
  }
  if (t < SCAN_BLK) boff[t] = temp[t] - v;
  if (t == SCAN_BLK - 1) row_start[N_NODES] = temp[t];
}

__global__ void k_scan_c(const int* __restrict__ excl, const int* __restrict__ boff,
                         int* __restrict__ row_start, int* __restrict__ cursor) {
  int i = blockIdx.x * 256 + threadIdx.x;
  if (i < N_NODES) {
    int e = excl[i] + boff[blockIdx.x];
    row_start[i] = e;
    cursor[i] = e;
  }
}

__global__ void k_fill(const int* __restrict__ edge, int* __restrict__ cursor,
                       int* __restrict__ csr_src) {
  int i = blockIdx.x * blockDim.x + threadIdx.x;
  if (i < NUM_EDGES) {
    int d = edge[NUM_EDGES + i];
    int p = atomicAdd(&cursor[d], 1);
    csr_src[p] = edge[i];
  }
}

// ---------------- encoder layer 1 (frozen) -----------------------------------------
__global__ void k_enc1(const float* __restrict__ x, const float* __restrict__ w1,
                       const float* __restrict__ b1, float* __restrict__ t) {
  __shared__ float W[6 * 256];
  __shared__ float xs[16][6];
  int tid = threadIdx.x;
  for (int i = tid; i < 6 * 256; i += 256) W[i] = w1[i];
  int base = blockIdx.x * 16;
  if (tid < 96) {
    int n = tid / 6, k = tid % 6;
    int node = base + n;
    xs[n][k] = (node < N_NODES) ? x[node * 16 + 4 + k] : 0.f;
  }
  __syncthreads();
  float b = b1[tid];
  for (int n = 0; n < 16; ++n) {
    int node = base + n;
    if (node >= N_NODES) break;
    float acc = 0.f;
#pragma unroll
    for (int k = 0; k < 6; ++k) acc = __fmaf_rn(xs[n][k], W[k * 256 + tid], acc);
    t[node * 256 + tid] = fmaxf(__fadd_rn(acc, b), 0.f);
  }
}

// ---------------- fp32 SIMT GEMM (frozen math; epilogue also emits bf16 copy) -------
__global__ __launch_bounds__(256, 2) void k_gemm_enc(
    const float* __restrict__ A, const float* __restrict__ W0,
    const float* __restrict__ bias, float* __restrict__ C,
    bf16_t* __restrict__ Cb, int M) {
  __shared__ float As[16][132];
  __shared__ float Ws[16][128];
  const int tid = threadIdx.x;
  const int tx = tid & 15;
  const int ty = tid >> 4;
  const int rowBase = blockIdx.x * 128;
  const int colBase = blockIdx.y * 128;

  float acc[2][2][4][4];
#pragma unroll
  for (int a = 0; a < 2; ++a)
#pragma unroll
    for (int b = 0; b < 2; ++b)
#pragma unroll
      for (int i = 0; i < 4; ++i)
#pragma unroll
        for (int j = 0; j < 4; ++j) acc[a][b][i][j] = 0.f;

  for (int kt = 0; kt < 16; ++kt) {
    const int kb = kt * 16;
#pragma unroll
    for (int l = 0; l < 2; ++l) {
      int idx = tid + l * 256;
      int m = idx >> 2;
      int kq = (idx & 3) * 4;
      int arow = rowBase + m;
      float4 av = make_float4(0.f, 0.f, 0.f, 0.f);
      if (arow < M) av = *reinterpret_cast<const float4*>(&A[arow * 256 + kb + kq]);
      As[kq + 0][m] = av.x; As[kq + 1][m] = av.y;
      As[kq + 2][m] = av.z; As[kq + 3][m] = av.w;
    }
#pragma unroll
    for (int l = 0; l < 2; ++l) {
      int idx = tid + l * 256;
      int k = idx >> 5;
      int nq = (idx & 31) * 4;
      float4 wv = *reinterpret_cast<const float4*>(&W0[(kb + k) * 256 + colBase + nq]);
      *reinterpret_cast<float4*>(&Ws[k][nq]) = wv;
    }
    __syncthreads();
#pragma unroll
    for (int k = 0; k < 16; ++k) {
      float4 a0 = *reinterpret_cast<const float4*>(&As[k][ty * 4]);
      float4 a1 = *reinterpret_cast<const float4*>(&As[k][64 + ty * 4]);
      float4 w0 = *reinterpret_cast<const float4*>(&Ws[k][tx * 4]);
      float4 w1 = *reinterpret_cast<const float4*>(&Ws[k][64 + tx * 4]);
      float ar[2][4] = {{a0.x, a0.y, a0.z, a0.w}, {a1.x, a1.y, a1.z, a1.w}};
      float wr[2][4] = {{w0.x, w0.y, w0.z, w0.w}, {w1.x, w1.y, w1.z, w1.w}};
#pragma unroll
      for (int ri = 0; ri < 2; ++ri)
#pragma unroll
        for (int i = 0; i < 4; ++i)
#pragma unroll
          for (int ci = 0; ci < 2; ++ci)
#pragma unroll
            for (int j = 0; j < 4; ++j)
              acc[ri][ci][i][j] = __fmaf_rn(ar[ri][i], wr[ci][j], acc[ri][ci][i][j]);
    }
    __syncthreads();
  }
  float4 bv0 = *reinterpret_cast<const float4*>(&bias[colBase + tx * 4]);
  float4 bv1 = *reinterpret_cast<const float4*>(&bias[colBase + 64 + tx * 4]);
  float bb[2][4] = {{bv0.x, bv0.y, bv0.z, bv0.w}, {bv1.x, bv1.y, bv1.z, bv1.w}};
#pragma unroll
  for (int ri = 0; ri < 2; ++ri) {
#pragma unroll
    for (int i = 0; i < 4; ++i) {
      int row = rowBase + ri * 64 + ty * 4 + i;
      if (row < M) {
#pragma unroll
        for (int ci = 0; ci < 2; ++ci) {
          float o[4];
#pragma unroll
          for (int j = 0; j < 4; ++j)
            o[j] = __fadd_rn(acc[ri][ci][i][j], bb[ci][j]);
          *reinterpret_cast<float4*>(&C[row * 256 + colBase + ci * 64 + tx * 4]) =
              make_float4(o[0], o[1], o[2], o[3]);
          ushort4 ob = make_ushort4(f2bf(o[0]), f2bf(o[1]), f2bf(o[2]), f2bf(o[3]));
          *reinterpret_cast<ushort4*>(&Cb[(size_t)row * 256 + colBase + ci * 64 + tx * 4]) = ob;
        }
      }
    }
  }
}

// ---------------- weight prep: transpose f32 [k][n] -> bf16 [n][k] ------------------
__global__ void k_wprep(const float* __restrict__ w_rel, const float* __restrict__ w_root,
                        bf16_t* __restrict__ WT) {
  __shared__ bf16_t tile[64][258];
  int m = blockIdx.x;
  int k0 = blockIdx.y * 64;
  const float* src = (m < 8) ? (w_rel + (size_t)m * 65536)
                             : (w_root + (size_t)(m - 8) * 65536);
  bf16_t* dst = WT + (size_t)m * 65536;
  int tid = threadIdx.x;
  for (int r = 0; r < 64; ++r)
    tile[r][tid] = f2bf(src[(k0 + r) * 256 + tid]);
  __syncthreads();
  for (int c = 0; c < 64; c += 8) {
    ushort4 lo, hi;
    lo.x = tile[c + 0][tid]; lo.y = tile[c + 1][tid];
    lo.z = tile[c + 2][tid]; lo.w = tile[c + 3][tid];
    hi.x = tile[c + 4][tid]; hi.y = tile[c + 5][tid];
    hi.z = tile[c + 6][tid]; hi.w = tile[c + 7][tid];
    *reinterpret_cast<ushort4*>(&dst[tid * 256 + k0 + c]) = lo;
    *reinterpret_cast<ushort4*>(&dst[tid * 256 + k0 + c + 4]) = hi;
  }
}

// ---------------- LDS-free MFMA bf16 GEMM core (BM=128, BN=256), bf16 out -----------
__device__ __forceinline__ void gemm_core(
    const bf16_t* __restrict__ A, const bf16_t* __restrict__ W0t,
    const bf16_t* __restrict__ B, const bf16_t* __restrict__ W1t,
    const float* __restrict__ bias, bf16_t* __restrict__ C, int rowBase) {
  const int tid = threadIdx.x;
  const int lane = tid & 63;
  const int wave = tid >> 6;
  const int lm = lane & 15;
  const int quad = lane >> 4;
  const int wm = (wave >> 1) * 64;
  const int wn = (wave & 1) * 128;

  f32x4 acc[4][8];
#pragma unroll
  for (int i = 0; i < 4; ++i)
#pragma unroll
    for (int j = 0; j < 8; ++j) acc[i][j] = (f32x4){0.f, 0.f, 0.f, 0.f};

#pragma unroll
  for (int phase = 0; phase < 2; ++phase) {
    const bf16_t* __restrict__ Ain = phase ? B : A;
    const bf16_t* __restrict__ Wt  = phase ? W1t : W0t;
    const bf16_t* ap[4];
    const bf16_t* bp[8];
#pragma unroll
    for (int i = 0; i < 4; ++i)
      ap[i] = Ain + (size_t)(rowBase + wm + i * 16 + lm) * 256 + quad * 8;
#pragma unroll
    for (int j = 0; j < 8; ++j)
      bp[j] = Wt + (size_t)(wn + j * 16 + lm) * 256 + quad * 8;
    for (int kt = 0; kt < 8; ++kt) {
      bf16x8 af[4], bfr[8];
#pragma unroll
      for (int i = 0; i < 4; ++i)
        af[i] = *reinterpret_cast<const bf16x8*>(ap[i] + kt * 32);
#pragma unroll
      for (int j = 0; j < 8; ++j)
        bfr[j] = *reinterpret_cast<const bf16x8*>(bp[j] + kt * 32);
#pragma unroll
      for (int i = 0; i < 4; ++i)
#pragma unroll
        for (int j = 0; j < 8; ++j)
          acc[i][j] = __builtin_amdgcn_mfma_f32_16x16x32_bf16(af[i], bfr[j], acc[i][j], 0, 0, 0);
    }
  }
  float bj[8];
#pragma unroll
  for (int j = 0; j < 8; ++j) bj[j] = bias[wn + j * 16 + lm];
#pragma unroll
  for (int i = 0; i < 4; ++i) {
#pragma unroll
    for (int j = 0; j < 8; ++j) {
      int col = wn + j * 16 + lm;
#pragma unroll
      for (int r = 0; r < 4; ++r) {
        int row = rowBase + wm + i * 16 + quad * 4 + r;
        C[(size_t)row * 256 + col] = f2bf(fmaxf(acc[i][j][r] + bj[j], 0.f));
      }
    }
  }
}

// pair-batched GEMM1: X1[slot] = relu(AGG@wr0_e + hb@wo0_e + br0_e), e = pe + slot
__global__ __launch_bounds__(256) void k_gemm1_b(
    const bf16_t* __restrict__ AGG, const bf16_t* __restrict__ hb,
    const bf16_t* __restrict__ WT, const float* __restrict__ b_rel,
    bf16_t* __restrict__ X1p, int pe) {
  int slot = blockIdx.y, e = pe + slot;
  gemm_core(AGG, WT + (size_t)(e * 2) * 65536,
            hb, WT + (size_t)(8 + e * 2) * 65536,
            b_rel + (size_t)(e * 2) * 256,
            X1p + (size_t)slot * M_PAD * 256, blockIdx.x * 128);
}

// pair-batched GEMM2 (in-place): X2[slot] = relu(A1[slot]@wr1_e + X1[slot]@wo1_e + br1_e)
__global__ __launch_bounds__(256) void k_gemm2_b(
    const bf16_t* __restrict__ A1p, bf16_t* __restrict__ X1p,
    const bf16_t* __restrict__ WT, const float* __restrict__ b_rel, int pe) {
  int slot = blockIdx.y, e = pe + slot;
  bf16_t* Xs = X1p + (size_t)slot * M_PAD * 256;
  gemm_core(A1p + (size_t)slot * M_PAD * 256, WT + (size_t)(e * 2 + 1) * 65536,
            Xs, WT + (size_t)(8 + e * 2 + 1) * 65536,
            b_rel + (size_t)(e * 2 + 1) * 256, Xs, blockIdx.x * 128);
}

// ---------------- CSR gather, bf16 in/out (f32 accumulate, unroll-2) ----------------
__device__ __forceinline__ void gather_core(
    const int* __restrict__ row_start, const int* __restrict__ csr_src,
    const bf16_t* __restrict__ X, bf16_t* __restrict__ Cout) {
  int tid = threadIdx.x;
  int r = blockIdx.x * 8 + (tid >> 5);
  int f = (tid & 31) * 8;
  int j0 = row_start[r], j1 = row_start[r + 1];
  float a[8] = {0.f, 0.f, 0.f, 0.f, 0.f, 0.f, 0.f, 0.f};
  int j = j0;
  for (; j + 1 < j1; j += 2) {
    int s0 = csr_src[j];
    int s1 = csr_src[j + 1];
    bf16x8 v0 = *reinterpret_cast<const bf16x8*>(&X[(size_t)s0 * 256 + f]);
    bf16x8 v1 = *reinterpret_cast<const bf16x8*>(&X[(size_t)s1 * 256 + f]);
#pragma unroll
    for (int t = 0; t < 8; ++t) a[t] += bf2f((unsigned short)v0[t]);
#pragma unroll
    for (int t = 0; t < 8; ++t) a[t] += bf2f((unsigned short)v1[t]);
  }
  if (j < j1) {
    int s = csr_src[j];
    bf16x8 v = *reinterpret_cast<const bf16x8*>(&X[(size_t)s * 256 + f]);
#pragma unroll
    for (int t = 0; t < 8; ++t) a[t] += bf2f((unsigned short)v[t]);
  }
  ushort4 lo = make_ushort4(f2bf(a[0]), f2bf(a[1]), f2bf(a[2]), f2bf(a[3]));
  ushort4 hi = make_ushort4(f2bf(a[4]), f2bf(a[5]), f2bf(a[6]), f2bf(a[7]));
  *reinterpret_cast<ushort4*>(&Cout[(size_t)r * 256 + f]) = lo;
  *reinterpret_cast<ushort4*>(&Cout[(size_t)r * 256 + f + 4]) = hi;
}

__global__ void k_gather(const int* __restrict__ row_start, const int* __restrict__ csr_src,
                         const bf16_t* __restrict__ X, bf16_t* __restrict__ Cout) {
  gather_core(row_start, csr_src, X, Cout);
}

__global__ void k_gather_b(const int* __restrict__ row_start, const int* __restrict__ csr_src,
                           const bf16_t* __restrict__ X1p, bf16_t* __restrict__ A1p) {
  size_t off = (size_t)blockIdx.y * M_PAD * 256;
  gather_core(row_start, csr_src, X1p + off, A1p + off);
}

// ---------------- numpy-faithful f32 router: LDS-free, 4 nodes/wave (r15 config) ----
// Per-(node,col) arithmetic BIT-IDENTICAL to r7..r18: ascending k chain, readlane
// h broadcast, global weight loads, gf-then-bias, pairwise-8 LN, f64 exp.
__global__ __launch_bounds__(256) void k_router_np(
    const float* __restrict__ h, const int* __restrict__ batch,
    const float* __restrict__ gf, const float* __restrict__ lnn,
    const float* __restrict__ rtw1, const float* __restrict__ rtb1,
    const float* __restrict__ lng, const float* __restrict__ lnb,
    const float* __restrict__ rtw2, const float* __restrict__ rtb2,
    const float* __restrict__ centers, float* __restrict__ sw) {
  __shared__ float sr[4][128];
  __shared__ float sa[4][128];
  __shared__ float sb[4][8];
  const int tid = threadIdx.x;
  const int w = tid >> 6;
  const int l = tid & 63;
  const int nbase = blockIdx.x * (4 * NPW) + w * NPW;   // grid = 3125, exact

  float hreg[NPW][4];
#pragma unroll
  for (int nn = 0; nn < NPW; ++nn) {
    int node = nbase + nn;
#pragma unroll
    for (int j = 0; j < 4; ++j)
      hreg[nn][j] = h[(size_t)node * 256 + j * 64 + l];
  }

  float acc0[NPW], acc1[NPW];
#pragma unroll
  for (int nn = 0; nn < NPW; ++nn) { acc0[nn] = 0.f; acc1[nn] = 0.f; }
#pragma unroll
  for (int j = 0; j < 4; ++j) {
#pragma unroll 16
    for (int k2 = 0; k2 < 64; ++k2) {
      int k = j * 64 + k2;
      float w0 = rtw1[k * RHD + l];
      float w1 = rtw1[k * RHD + l + 64];
#pragma unroll
      for (int nn = 0; nn < NPW; ++nn) {
        float hv = readlane_f(hreg[nn][j], k2);
        acc0[nn] = __fmaf_rn(hv, w0, acc0[nn]);
        acc1[nn] = __fmaf_rn(hv, w1, acc1[nn]);
      }
    }
  }

  float g0a = rtw1[256 * RHD + l],      g1a = rtw1[257 * RHD + l];
  float g0b = rtw1[256 * RHD + l + 64], g1b = rtw1[257 * RHD + l + 64];
  float b0 = rtb1[l], b1v = rtb1[l + 64];
  float lga = lng[l], lgb = lng[l + 64];
  float lba = lnb[l], lbb = lnb[l + 64];

  for (int nn = 0; nn < NPW; ++nn) {
    int node = nbase + nn;
    int g = batch[node];
    float gf0 = gf[g * 2 + 0], gf1 = gf[g * 2 + 1], nl = lnn[g];
    float t0 = acc0[nn], t1 = acc1[nn];
    t0 = __fmaf_rn(gf0, g0a, t0);
    t0 = __fmaf_rn(gf1, g1a, t0);
    t1 = __fmaf_rn(gf0, g0b, t1);
    t1 = __fmaf_rn(gf1, g1b, t1);
    float r0 = __fadd_rn(t0, b0);
    float r1 = __fadd_rn(t1, b1v);
    __syncthreads();
    sr[w][l] = r0; sr[w][l + 64] = r1;
    __syncthreads();

    float aj = 0.f;
    if (l < 8) {
      aj = sr[w][l];
      for (int i = 8; i < 128; i += 8) aj = __fadd_rn(aj, sr[w][i + l]);
    }
    {
      float a0 = __shfl(aj, 0, 64), a1 = __shfl(aj, 1, 64);
      float a2 = __shfl(aj, 2, 64), a3 = __shfl(aj, 3, 64);
      float a4 = __shfl(aj, 4, 64), a5 = __shfl(aj, 5, 64);
      float a6 = __shfl(aj, 6, 64), a7 = __shfl(aj, 7, 64);
      float s01 = __fadd_rn(a0, a1), s23 = __fadd_rn(a2, a3);
      float s45 = __fadd_rn(a4, a5), s67 = __fadd_rn(a6, a7);
      aj = __fadd_rn(__fadd_rn(s01, s23), __fadd_rn(s45, s67));
    }
    float mu = __fdiv_rn(aj, 128.0f);
    float d0 = __fsub_rn(r0, mu), d1 = __fsub_rn(r1, mu);
    sr[w][l] = __fmul_rn(d0, d0);
    sr[w][l + 64] = __fmul_rn(d1, d1);
    __syncthreads();
    float qj = 0.f;
    if (l < 8) {
      qj = sr[w][l];
      for (int i = 8; i < 128; i += 8) qj = __fadd_rn(qj, sr[w][i + l]);
    }
    {
      float a0 = __shfl(qj, 0, 64), a1 = __shfl(qj, 1, 64);
      float a2 = __shfl(qj, 2, 64), a3 = __shfl(qj, 3, 64);
      float a4 = __shfl(qj, 4, 64), a5 = __shfl(qj, 5, 64);
      float a6 = __shfl(qj, 6, 64), a7 = __shfl(qj, 7, 64);
      float s01 = __fadd_rn(a0, a1), s23 = __fadd_rn(a2, a3);
      float s45 = __fadd_rn(a4, a5), s67 = __fadd_rn(a6, a7);
      qj = __fadd_rn(__fadd_rn(s01, s23), __fadd_rn(s45, s67));
    }
    float var = __fdiv_rn(qj, 128.0f);
    float inv = __fdiv_rn(1.0f, sqrtf(__fadd_rn(var, 1e-5f)));
    float y0 = __fadd_rn(__fmul_rn(__fmul_rn(d0, inv), lga), lba);
    float y1 = __fadd_rn(__fmul_rn(__fmul_rn(d1, inv), lgb), lbb);
    sa[w][l] = fmaxf(y0, 0.f);
    sa[w][l + 64] = fmaxf(y1, 0.f);
    __syncthreads();

    if (l < 4) {
      float acc = 0.f;
      for (int k = 0; k < 128; ++k) acc = __fmaf_rn(sa[w][k], rtw2[k * 4 + l], acc);
      float lrn = __fadd_rn(acc, rtb2[l]);
      float dd = __fsub_rn(nl, centers[l]);
      float pr = -__fmul_rn(dd, dd);
      sb[w][4 + l] = __fadd_rn(__fmul_rn(0.65f, lrn), __fmul_rn(0.35f, pr));
    }
    __syncthreads();

    if (l == 0) {
      float lg[4] = {sb[w][4], sb[w][5], sb[w][6], sb[w][7]};
      float mx = fmaxf(fmaxf(lg[0], lg[1]), fmaxf(lg[2], lg[3]));
      float e[4];
#pragma unroll
      for (int c = 0; c < 4; ++c)
        e[c] = (float)exp((double)__fsub_rn(lg[c], mx));
      float S = __fadd_rn(__fadd_rn(__fadd_rn(e[0], e[1]), e[2]), e[3]);
      float p[4];
#pragma unroll
      for (int c = 0; c < 4; ++c) p[c] = __fdiv_rn(e[c], S);
      int i1 = 0;
#pragma unroll
      for (int c = 1; c < 4; ++c) if (p[c] > p[i1]) i1 = c;
      int i2 = -1;
#pragma unroll
      for (int c = 0; c < 4; ++c) {
        if (c == i1) continue;
        if (i2 < 0 || p[c] > p[i2]) i2 = c;
      }
      float den = __fadd_rn(__fadd_rn(p[i1], p[i2]), 1e-8f);
      float swv[4] = {0.f, 0.f, 0.f, 0.f};
      swv[i1] = __fdiv_rn(p[i1], den);
      swv[i2] = __fdiv_rn(p[i2], den);
      *reinterpret_cast<float4*>(&sw[node * 4]) =
          make_float4(swv[0], swv[1], swv[2], swv[3]);
    }
  }
}

// ---------------- head stage 1 (pair-batched): PQ[n][e*16 + {0..5, 8..13}] ---------
__global__ void k_headPQ_b(const bf16_t* __restrict__ X2p,
                           const float* __restrict__ w_relo, const float* __restrict__ w_rooto,
                           float* __restrict__ PQ, int pe) {
  int slot = blockIdx.y, e = pe + slot;
  const bf16_t* X2 = X2p + (size_t)slot * M_PAD * 256;
  const float* wro = w_relo + (size_t)e * 256 * OUTD;
  const float* wto = w_rooto + (size_t)e * 256 * OUTD;
  int tid = threadIdx.x;
  int r = blockIdx.x * 4 + (tid >> 6);    // grid.x = N/4 exact
  int lane = tid & 63;
  int k0 = lane * 4;
  float wr_[24], wt_[24];
#pragma unroll
  for (int q = 0; q < 6; ++q) {
    float4 a = *reinterpret_cast<const float4*>(&wro[k0 * 6 + q * 4]);
    wr_[q * 4 + 0] = a.x; wr_[q * 4 + 1] = a.y; wr_[q * 4 + 2] = a.z; wr_[q * 4 + 3] = a.w;
    float4 b = *reinterpret_cast<const float4*>(&wto[k0 * 6 + q * 4]);
    wt_[q * 4 + 0] = b.x; wt_[q * 4 + 1] = b.y; wt_[q * 4 + 2] = b.z; wt_[q * 4 + 3] = b.w;
  }
  ushort4 xv4 = *reinterpret_cast<const ushort4*>(&X2[(size_t)r * 256 + k0]);
  float xv[4] = {bf2f(xv4.x), bf2f(xv4.y), bf2f(xv4.z), bf2f(xv4.w)};
  float p[12] = {0.f, 0.f, 0.f, 0.f, 0.f, 0.f, 0.f, 0.f, 0.f, 0.f, 0.f, 0.f};
#pragma unroll
  for (int jj = 0; jj < 4; ++jj)
#pragma unroll
    for (int c = 0; c < 6; ++c) {
      p[c]     += xv[jj] * wr_[jj * 6 + c];
      p[6 + c] += xv[jj] * wt_[jj * 6 + c];
    }
#pragma unroll
  for (int off = 32; off > 0; off >>= 1)
#pragma unroll
    for (int c = 0; c < 12; ++c) p[c] += __shfl_down(p[c], off, 64);
  if (lane == 0) {
#pragma unroll
    for (int c = 0; c < 6; ++c) {
      PQ[(size_t)r * 64 + e * 16 + c] = p[c];
      PQ[(size_t)r * 64 + e * 16 + 8 + c] = p[6 + c];
    }
  }
}

// ---------------- head stage 2 (all experts, single kernel) -------------------------
__global__ void k_headfin_all(const int* __restrict__ row_start,
                              const int* __restrict__ csr_src,
                              const float* __restrict__ PQ, const float* __restrict__ b_relo,
                              const float* __restrict__ sw, float* __restrict__ out) {
  int t = blockIdx.x * 256 + threadIdx.x;
  int n = t >> 3, c = t & 7;
  if (n >= N_NODES || c >= 6) return;
  int j0 = row_start[n], j1 = row_start[n + 1];
  float av0 = 0.f, av1 = 0.f, av2 = 0.f, av3 = 0.f;
  for (int j = j0; j < j1; ++j) {
    size_t base = (size_t)csr_src[j] * 64 + c;
    av0 += PQ[base];
    av1 += PQ[base + 16];
    av2 += PQ[base + 32];
    av3 += PQ[base + 48];
  }
  float4 s4 = *reinterpret_cast<const float4*>(&sw[n * 4]);
  size_t nb = (size_t)n * 64 + c;
  float v = s4.x * (av0 + b_relo[0 * 6 + c] + PQ[nb + 8]);
  v += s4.y * (av1 + b_relo[1 * 6 + c] + PQ[nb + 16 + 8]);
  v += s4.z * (av2 + b_relo[2 * 6 + c] + PQ[nb + 32 + 8]);
  v += s4.w * (av3 + b_relo[3 * 6 + c] + PQ[nb + 48 + 8]);
  out[n * 6 + c] = v;
}

// ---------------- launch ----------------
extern "C" void kernel_launch(void* const* d_in, const int* in_sizes, int n_in,
                              void* d_out, int out_size, void* d_ws, size_t ws_size,
                              hipStream_t stream) {
  const float* x        = (const float*)d_in[0];
  const int*   edge     = (const int*)d_in[1];
  const int*   batch    = (const int*)d_in[2];
  const float* enc_w1   = (const float*)d_in[4];
  const float* enc_b1   = (const float*)d_in[5];
  const float* enc_w2   = (const float*)d_in[6];
  const float* enc_b2   = (const float*)d_in[7];
  const float* rt_w1    = (const float*)d_in[8];
  const float* rt_b1    = (const float*)d_in[9];
  const float* ln_g     = (const float*)d_in[10];
  const float* ln_b     = (const float*)d_in[11];
  const float* rt_w2    = (const float*)d_in[12];
  const float* rt_b2    = (const float*)d_in[13];
  const float* centers  = (const float*)d_in[14];
  const float* w_rel    = (const float*)d_in[15];
  const float* b_rel    = (const float*)d_in[16];
  const float* w_root   = (const float*)d_in[17];
  const float* w_relo   = (const float*)d_in[18];
  const float* b_relo   = (const float*)d_in[19];
  const float* w_rooto  = (const float*)d_in[20];
  float* out = (float*)d_out;

  char* wsp = (char*)d_ws;
  auto alloc = [&](size_t bytes) -> char* {
    char* p = wsp;
    wsp += (bytes + 255) & ~(size_t)255;
    return p;
  };
  const size_t actF32 = (size_t)M_PAD * 256 * sizeof(float);    // 51.25 MB
  const size_t actB16 = (size_t)M_PAD * 256 * sizeof(bf16_t);   // 25.63 MB
  char*   hx  = alloc(actF32);    // h; doubles as X1/X2 pair after router
  float*  h   = (float*)hx;
  bf16_t* X1p = (bf16_t*)hx;
  char*   tx  = alloc(actF32);    // t; doubles as A1 pair after encoder GEMM
  float*  t   = (float*)tx;
  bf16_t* A1p = (bf16_t*)tx;
  bf16_t* hb  = (bf16_t*)alloc(actB16);
  bf16_t* AGG = (bf16_t*)alloc(actB16);
  bf16_t* WT  = (bf16_t*)alloc((size_t)16 * 65536 * sizeof(bf16_t));
  float* PQ   = (float*)alloc((size_t)N_NODES * 64 * sizeof(float));   // 12.8 MB
  float* swp  = (float*)alloc((size_t)N_NODES * 4 * sizeof(float));
  int*   n_cnt = (int*)alloc(NG * sizeof(int));
  int*   e_cnt = (int*)alloc(NG * sizeof(int));
  float* gfbuf = (float*)alloc(NG * 2 * sizeof(float));
  float* lnn   = (float*)alloc(NG * sizeof(float));
  int* deg       = (int*)alloc((size_t)N_NODES * sizeof(int));
  int* row_start = (int*)alloc((size_t)(N_NODES + 1) * sizeof(int));
  int* cursor    = (int*)alloc((size_t)N_NODES * sizeof(int));
  int* excl      = (int*)alloc((size_t)N_NODES * sizeof(int));
  int* bsum      = (int*)alloc(SCAN_BLK * sizeof(int));
  int* boff      = (int*)alloc(SCAN_BLK * sizeof(int));
  int* csr_src   = (int*)alloc((size_t)NUM_EDGES * sizeof(int));

  // graph stats + CSR build + weight prep
  k_zero<<<(N_NODES + 255) / 256, 256, 0, stream>>>(deg, n_cnt, e_cnt);
  k_count<<<(NUM_EDGES + 255) / 256, 256, 0, stream>>>(batch, edge, n_cnt, e_cnt, deg);
  k_graph_stats<<<1, 64, 0, stream>>>(n_cnt, e_cnt, gfbuf, lnn);
  k_scan_a<<<SCAN_BLK, 256, 0, stream>>>(deg, excl, bsum);
  k_scan_b<<<1, 256, 0, stream>>>(bsum, boff, row_start);
  k_scan_c<<<SCAN_BLK, 256, 0, stream>>>(excl, boff, row_start, cursor);
  k_fill<<<(NUM_EDGES + 255) / 256, 256, 0, stream>>>(edge, cursor, csr_src);
  dim3 wgrid(16, 4);
  k_wprep<<<wgrid, 256, 0, stream>>>(w_rel, w_root, WT);

  // encoder (frozen math; epilogue also writes hb)
  k_enc1<<<(N_NODES + 15) / 16, 256, 0, stream>>>(x, enc_w1, enc_b1, t);
  dim3 egrid(M_PAD / 128, 2);
  k_gemm_enc<<<egrid, 256, 0, stream>>>(t, enc_w2, enc_b2, h, hb, N_NODES);

  // router (4 nodes/wave, r15 config; bit-identical arithmetic)
  k_router_np<<<N_NODES / (4 * NPW), 256, 0, stream>>>(
      h, batch, gfbuf, lnn, rt_w1, rt_b1, ln_g, ln_b, rt_w2, rt_b2, centers, swp);

  // loop-invariant agg_h (after router: X1p will overwrite h)
  k_gather<<<N_NODES / 8, 256, 0, stream>>>(row_start, csr_src, hb, AGG);

  // experts, pair-batched (gridDim.y = 2)
  dim3 ggrid(M_PAD / 128, 2);
  dim3 grid_gather(N_NODES / 8, 2);
  dim3 grid_pq(N_NODES / 4, 2);
  for (int pe = 0; pe < NEXP; pe += 2) {
    k_gemm1_b<<<ggrid, 256, 0, stream>>>(AGG, hb, WT, b_rel, X1p, pe);
    k_gather_b<<<grid_gather, 256, 0, stream>>>(row_start, csr_src, X1p, A1p);
    k_gemm2_b<<<ggrid, 256, 0, stream>>>(A1p, X1p, WT, b_rel, pe);
    k_headPQ_b<<<grid_pq, 256, 0, stream>>>(X1p, w_relo, w_rooto, PQ, pe);
  }
  k_headfin_all<<<(N_NODES * 8 + 255) / 256, 256, 0, stream>>>(
      row_start, csr_src, PQ, b_relo, swp, out);
}